// Round 4
// baseline (4655.948 us; speedup 1.0000x reference)
//
#include <hip/hip_runtime.h>
#include <math.h>

typedef unsigned long long ull;

// ---------------------------------------------------------------------------
// stem: F0[b,o,n] = stem_w[o,:] . xyz[b,:,n] + stem_b[o]
// ---------------------------------------------------------------------------
__global__ __launch_bounds__(256) void stem_kernel(const float* __restrict__ xyz,
    const float* __restrict__ w, const float* __restrict__ bias,
    float* __restrict__ F0, int N){
  int id = blockIdx.x*256 + threadIdx.x;
  int n = id % N; int b = id / N;
  float x = xyz[((size_t)b*3+0)*N+n];
  float y = xyz[((size_t)b*3+1)*N+n];
  float z = xyz[((size_t)b*3+2)*N+n];
  #pragma unroll
  for (int o=0;o<8;o++){
    float v = fmaf(w[o*3+0],x, fmaf(w[o*3+1],y, fmaf(w[o*3+2],z, bias[o])));
    F0[((size_t)b*8+o)*N+n] = v;
  }
}

// ---------------------------------------------------------------------------
// KNN: per-thread top-16 over a candidate split; partials stored TRANSPOSED
// (row e = s*16+u, col qg) so both write and merge-read are coalesced.
// Distance mirrors reference: (qq + pp) - 2*dot, non-contracted IEEE ops.
// ---------------------------------------------------------------------------
__global__ __launch_bounds__(256) void knn_kernel(
    const float* __restrict__ Pq, const float* __restrict__ Pp,
    float* __restrict__ part_d, int* __restrict__ part_i,
    int Nq, int Np, int CAND, int total){
  __shared__ float4 tile[256];
  int qg = blockIdx.x*256 + threadIdx.x;
  int b  = qg / Nq, qn = qg % Nq;
  int s  = blockIdx.y;
  const float* Pqb = Pq + (size_t)b*3*Nq;
  const float* Ppb = Pp + (size_t)b*3*Np;
  float qx = Pqb[qn], qy = Pqb[Nq+qn], qz = Pqb[2*Nq+qn];
  float qq = __fadd_rn(__fadd_rn(__fmul_rn(qx,qx),__fmul_rn(qy,qy)),__fmul_rn(qz,qz));

  float dl[16]; int il[16];
  #pragma unroll
  for (int u=0;u<16;u++){ dl[u]=INFINITY; il[u]=-1; }
  float maxd = INFINITY; int maxslot = 0;

  int c0 = s*CAND;
  for (int tb=0; tb<CAND; tb+=256){
    int p = c0 + tb + threadIdx.x;
    float px = Ppb[p], py = Ppb[Np+p], pz = Ppb[2*Np+p];
    float pp = __fadd_rn(__fadd_rn(__fmul_rn(px,px),__fmul_rn(py,py)),__fmul_rn(pz,pz));
    __syncthreads();
    tile[threadIdx.x] = make_float4(px,py,pz,pp);
    __syncthreads();
    for (int j=0;j<256;j++){
      float4 c = tile[j];
      float dot = __fadd_rn(__fadd_rn(__fmul_rn(qx,c.x),__fmul_rn(qy,c.y)),__fmul_rn(qz,c.z));
      float dc  = __fsub_rn(__fadd_rn(qq,c.w), __fmul_rn(2.0f,dot));
      if (dc < maxd){
        int pidx = c0 + tb + j;
        #pragma unroll
        for (int u=0;u<16;u++){ bool sel=(maxslot==u); dl[u]=sel?dc:dl[u]; il[u]=sel?pidx:il[u]; }
        maxd = dl[0]; maxslot = 0;
        #pragma unroll
        for (int u=1;u<16;u++){ bool g=(dl[u]>maxd); maxd=g?dl[u]:maxd; maxslot=g?u:maxslot; }
      }
    }
  }
  #pragma unroll
  for (int u=0;u<16;u++){
    size_t row = (size_t)(s*16+u);
    part_d[row*total + qg] = dl[u];
    part_i[row*total + qg] = il[u];
  }
}

// merge transposed partials -> final 16 (lex (d, idx) smallest); coalesced reads
__global__ __launch_bounds__(256) void knn_merge(const float* __restrict__ part_d,
    const int* __restrict__ part_i, int* __restrict__ idxk, int rows, int total){
  int qg = blockIdx.x*256 + threadIdx.x;
  if (qg >= total) return;
  float dl[16]; int il[16];
  #pragma unroll
  for (int u=0;u<16;u++){ dl[u]=INFINITY; il[u]=0x7fffffff; }
  float maxd = INFINITY; int maxi = 0x7fffffff; int maxslot = 0;
  for (int e=0;e<rows;e++){
    float d = part_d[(size_t)e*total + qg];
    int  ii = part_i[(size_t)e*total + qg];
    bool better = (d < maxd) || (d == maxd && ii < maxi);
    if (better){
      #pragma unroll
      for (int u=0;u<16;u++){ bool sel=(maxslot==u); dl[u]=sel?d:dl[u]; il[u]=sel?ii:il[u]; }
      maxd = dl[0]; maxi = il[0]; maxslot = 0;
      #pragma unroll
      for (int u=1;u<16;u++){
        bool g = (dl[u]>maxd) || (dl[u]==maxd && il[u]>maxi);
        maxd=g?dl[u]:maxd; maxi=g?il[u]:maxi; maxslot=g?u:maxslot;
      }
    }
  }
  #pragma unroll
  for (int u=0;u<16;u++) idxk[(size_t)qg*16+u] = il[u];
}

// ---------------------------------------------------------------------------
// EdgeConv pre-activation
// ---------------------------------------------------------------------------
template<int CIN, int COUT>
__global__ __launch_bounds__(1024) void edge_conv_pre(
    const float* __restrict__ Fk, const float* __restrict__ Fi,
    const int* __restrict__ idx, const float* __restrict__ W,
    float* __restrict__ pre, int Nq, int Np){
  constexpr int C2  = 2*CIN;
  constexpr int PAD = C2 + 4;
  constexpr int TO  = (COUT <= 64) ? COUT : 64;
  constexpr int OP  = COUT / TO;
  extern __shared__ float sm[];
  float* Wl = sm;
  float* Pl = sm + COUT*PAD;
  int t = threadIdx.x;
  int n = blockIdx.x, b = blockIdx.y;
  for (int e=t; e<COUT*C2; e += blockDim.x){
    int o=e/C2, c=e%C2; Wl[o*PAD+c] = W[e];
  }
  const int* idxn = idx + ((size_t)b*Nq + n)*16;
  for (int e=t; e<16*C2; e += blockDim.x){
    int k = e/C2, c = e%C2;
    int cc = (c < CIN) ? c : (c-CIN);
    float fi = Fi[((size_t)b*CIN + cc)*Nq + n];
    float v;
    if (c < CIN){ int nb = idxn[k]; v = Fk[((size_t)b*CIN + c)*Np + nb] - fi; }
    else v = fi;
    Pl[k*PAD+c] = v;
  }
  __syncthreads();
  int k = t & 15, o0 = t >> 4;
  #pragma unroll
  for (int op=0; op<OP; op++){
    int o = o0 + op*TO;
    float acc = 0.f;
    #pragma unroll
    for (int c=0;c<C2;c+=4){
      float4 wv = *(const float4*)&Wl[o*PAD+c];
      float4 pv = *(const float4*)&Pl[k*PAD+c];
      acc = fmaf(wv.x,pv.x,acc); acc = fmaf(wv.y,pv.y,acc);
      acc = fmaf(wv.z,pv.z,acc); acc = fmaf(wv.w,pv.w,acc);
    }
    pre[(((size_t)b*COUT + o)*Nq + n)*16 + k] = acc;
  }
}

// GroupNorm stats
__global__ __launch_bounds__(256) void gn_reduce(const float* __restrict__ pre,
    double* __restrict__ gsum, int slabLen){
  int b = blockIdx.z, g = blockIdx.y;
  size_t base = ((size_t)(b*8+g))*slabLen;
  int chunkLen = slabLen / gridDim.x;
  const float* p = pre + base + (size_t)blockIdx.x*chunkLen;
  double s=0.0, sq=0.0;
  for (int i = threadIdx.x*4; i < chunkLen; i += 1024){
    float4 v = *(const float4*)(p+i);
    s += (double)v.x; sq = fma((double)v.x,(double)v.x,sq);
    s += (double)v.y; sq = fma((double)v.y,(double)v.y,sq);
    s += (double)v.z; sq = fma((double)v.z,(double)v.z,sq);
    s += (double)v.w; sq = fma((double)v.w,(double)v.w,sq);
  }
  #pragma unroll
  for (int off=32; off>=1; off>>=1){ s += __shfl_down(s, off); sq += __shfl_down(sq, off); }
  __shared__ double ls[4], lq[4];
  int wid = threadIdx.x>>6;
  if ((threadIdx.x&63)==0){ ls[wid]=s; lq[wid]=sq; }
  __syncthreads();
  if (threadIdx.x==0){
    double S=ls[0]+ls[1]+ls[2]+ls[3], Q=lq[0]+lq[1]+lq[2]+lq[3];
    atomicAdd(&gsum[(b*8+g)*2],   S);
    atomicAdd(&gsum[(b*8+g)*2+1], Q);
  }
}

// normalize + affine + relu + max over K
template<int COUT>
__global__ __launch_bounds__(256) void gn_act_max(const float* __restrict__ pre,
    const double* __restrict__ gsum, const float* __restrict__ gamma,
    const float* __restrict__ beta, float* __restrict__ outF, int Nq){
  int id = blockIdx.x*256 + threadIdx.x;
  int o = (id/Nq)%COUT; int b = id/(Nq*COUT);
  int g = o/(COUT/8);
  double s = gsum[(b*8+g)*2], sq = gsum[(b*8+g)*2+1];
  double cnt = (double)(COUT/8)*Nq*16.0;
  double mu  = s/cnt;
  double var = sq/cnt - mu*mu;
  float muf=(float)mu, rstd=(float)(1.0/sqrt(var+1e-5));
  float ga=gamma[o], be=beta[o];
  const float4* p = (const float4*)(pre + (size_t)id*16);
  float m = 0.f;
  #pragma unroll
  for (int q=0;q<4;q++){
    float4 v = p[q];
    m = fmaxf(m, fmaf((v.x-muf)*rstd, ga, be));
    m = fmaxf(m, fmaf((v.y-muf)*rstd, ga, be));
    m = fmaxf(m, fmaf((v.z-muf)*rstd, ga, be));
    m = fmaxf(m, fmaf((v.w-muf)*rstd, ga, be));
  }
  outF[id] = m;
}

// ---------------------------------------------------------------------------
// FPS v3: Morton-sorted ownership + exact per-thread bbox pruning.
// dist update is skipped only when provably a bit-exact no-op
// (0.999*lb > maxdist; margin >> 4-ulp rounding of the 8-op dist chain).
// Selection: per-thread tracks (maxdist, min ORIGINAL idx, coords) branchlessly;
// wave DPP max + ballot (+ rare tie loop); block key (dbits<<32)|~idx == stable
// argmax of the reference. Arithmetic identical to reference (non-contracted).
// ---------------------------------------------------------------------------
template<int CTRL>
__device__ __forceinline__ float dpp_maxf(float x){
  int y = __builtin_amdgcn_update_dpp(0, __float_as_int(x), CTRL, 0xf, 0xf, true);
  return fmaxf(x, __int_as_float(y));
}
__device__ __forceinline__ unsigned expandb(unsigned v){
  v &= 0x3FF;
  v = (v | (v<<16)) & 0x030000FF;
  v = (v | (v<<8))  & 0x0300F00F;
  v = (v | (v<<4))  & 0x030C30C3;
  v = (v | (v<<2))  & 0x09249249;
  return v;
}

template<int PPT, int BLK, int M>
__global__ __launch_bounds__(BLK) void fps_kernel(const float* __restrict__ P,
    int* __restrict__ idx_out){
  constexpr int N  = PPT*BLK;
  constexpr int NW = BLK/64;
  extern __shared__ __align__(16) unsigned smu[];
  unsigned* keys = smu;                       // N u32
  ull*     wk    = (ull*)&smu[N];             // 2*NW
  float4*  wc    = (float4*)(wk + 2*NW);      // 2*NW
  int b = blockIdx.x, t = threadIdx.x;
  const float* Pb = P + (size_t)b*3*N;

  // --- Morton keys (18-bit cell | 13-bit idx), coalesced load
  for (int i=t; i<N; i+=BLK){
    float x = Pb[i], y = Pb[N+i], z = Pb[2*N+i];
    int cx = (int)(__fadd_rn(x,8.f)*4.f); cx = cx<0?0:(cx>63?63:cx);
    int cy = (int)(__fadd_rn(y,8.f)*4.f); cy = cy<0?0:(cy>63?63:cy);
    int cz = (int)(__fadd_rn(z,8.f)*4.f); cz = cz<0?0:(cz>63?63:cz);
    unsigned mo = (expandb(cx)<<2) | (expandb(cy)<<1) | expandb(cz);
    keys[i] = (mo<<13) | (unsigned)i;
  }
  // --- bitonic sort (u32), uniform barriers
  for (unsigned k=2; k<=(unsigned)N; k<<=1){
    for (unsigned j=k>>1; j>0; j>>=1){
      __syncthreads();
      for (int i=t; i<N; i+=BLK){
        unsigned ixj = (unsigned)i ^ j;
        if (ixj > (unsigned)i){
          unsigned a = keys[i], c = keys[ixj];
          bool up = ((i & k) == 0);
          if ((a > c) == up){ keys[i]=c; keys[ixj]=a; }
        }
      }
    }
  }
  __syncthreads();

  // --- ownership: PPT sorted-consecutive points; gather coords, bbox
  int oidx[PPT]; float px[PPT], py[PPT], pz[PPT], dist[PPT];
  #pragma unroll
  for (int j=0;j<PPT;j++){
    oidx[j] = (int)(keys[t*PPT+j] & 0x1FFF);
    px[j] = Pb[oidx[j]]; py[j] = Pb[N+oidx[j]]; pz[j] = Pb[2*N+oidx[j]];
  }
  float bxmn=px[0],bxmx=px[0],bymn=py[0],bymx=py[0],bzmn=pz[0],bzmx=pz[0];
  #pragma unroll
  for (int j=1;j<PPT;j++){
    bxmn=fminf(bxmn,px[j]); bxmx=fmaxf(bxmx,px[j]);
    bymn=fminf(bymn,py[j]); bymx=fmaxf(bymx,py[j]);
    bzmn=fminf(bzmn,pz[j]); bzmx=fmaxf(bzmx,pz[j]);
  }

  // --- init distances to point with ORIGINAL index 0
  float sx = Pb[0], sy = Pb[N], sz = Pb[2*N];
  float bd = -1.f; int bi = 0x7fffffff; float bx=0.f, by=0.f, bz=0.f;
  #pragma unroll
  for (int j=0;j<PPT;j++){
    float dx=__fsub_rn(px[j],sx), dy=__fsub_rn(py[j],sy), dz=__fsub_rn(pz[j],sz);
    float dd=__fadd_rn(__fadd_rn(__fmul_rn(dx,dx),__fmul_rn(dy,dy)),__fmul_rn(dz,dz));
    dist[j]=dd;
    bool gt = dd > bd, eq = dd == bd;
    int mn = min(bi, oidx[j]);
    bd = gt?dd:bd; bx = gt?px[j]:bx; by = gt?py[j]:by; bz = gt?pz[j]:bz;
    bi = gt?oidx[j]:(eq?mn:bi);
  }
  if (t==0) idx_out[(size_t)b*M] = 0;

  int wid = t>>6, lane = t&63, par = 0;
  for (int i=1;i<M;i++){
    // wave argmax (value), result lane 63
    float r = bd;
    r = dpp_maxf<0x111>(r); r = dpp_maxf<0x112>(r);
    r = dpp_maxf<0x114>(r); r = dpp_maxf<0x118>(r);
    r = dpp_maxf<0x142>(r); r = dpp_maxf<0x143>(r);
    float wmax = __int_as_float(__builtin_amdgcn_readlane(__float_as_int(r), 63));
    ull msk = __ballot(bd == wmax);
    int bestl = __ffsll(msk) - 1;
    int wbi = __builtin_amdgcn_readlane(bi, bestl);
    ull rest = msk & (msk-1);
    if (rest){                                  // rare: cross-lane dist tie
      while (rest){
        int l = __ffsll(rest)-1; rest &= rest-1;
        int c = __builtin_amdgcn_readlane(bi, l);
        if (c < wbi){ wbi = c; bestl = l; }
      }
    }
    float wx = __int_as_float(__builtin_amdgcn_readlane(__float_as_int(bx), bestl));
    float wy = __int_as_float(__builtin_amdgcn_readlane(__float_as_int(by), bestl));
    float wz = __int_as_float(__builtin_amdgcn_readlane(__float_as_int(bz), bestl));
    if (lane==0){
      wk[par*NW+wid] = ((ull)__float_as_uint(wmax)<<32) | (unsigned)(~(unsigned)wbi);
      wc[par*NW+wid] = make_float4(wx,wy,wz,0.f);
    }
    __syncthreads();
    ull best = wk[par*NW]; int bw = 0;
    #pragma unroll
    for (int w=1;w<NW;w++){ ull o = wk[par*NW+w]; if (o > best){ best=o; bw=w; } }
    float4 sc = wc[par*NW+bw];
    if (t==0) idx_out[(size_t)b*M + i] = (int)(~(unsigned)best);
    par ^= 1;
    // exact prune: skip when every owned dd >= dist (no-op min)
    float ex = fmaxf(fmaxf(__fsub_rn(bxmn,sc.x), __fsub_rn(sc.x,bxmx)), 0.f);
    float ey = fmaxf(fmaxf(__fsub_rn(bymn,sc.y), __fsub_rn(sc.y,bymx)), 0.f);
    float ez = fmaxf(fmaxf(__fsub_rn(bzmn,sc.z), __fsub_rn(sc.z,bzmx)), 0.f);
    float lb = ex*ex + ey*ey + ez*ez;
    if (!(lb*0.999f > bd)){
      float nbd = -1.f; int nbi = 0x7fffffff; float nbx=0.f, nby=0.f, nbz=0.f;
      #pragma unroll
      for (int j=0;j<PPT;j++){
        float dx=__fsub_rn(px[j],sc.x), dy=__fsub_rn(py[j],sc.y), dz=__fsub_rn(pz[j],sc.z);
        float dd=__fadd_rn(__fadd_rn(__fmul_rn(dx,dx),__fmul_rn(dy,dy)),__fmul_rn(dz,dz));
        float nd = fminf(dist[j], dd);
        dist[j] = nd;
        bool gt = nd > nbd, eq = nd == nbd;
        int mn = min(nbi, oidx[j]);
        nbd = gt?nd:nbd; nbx = gt?px[j]:nbx; nby = gt?py[j]:nby; nbz = gt?pz[j]:nbz;
        nbi = gt?oidx[j]:(eq?mn:nbi);
      }
      bd=nbd; bi=nbi; bx=nbx; by=nby; bz=nbz;
    }
  }
}

// gather
__global__ __launch_bounds__(256) void gather_kernel(float* __restrict__ dst,
    const float* __restrict__ src, const int* __restrict__ idx,
    int C, int Nsrc, int M){
  int id = blockIdx.x*256 + threadIdx.x;
  int m = id % M; int c = (id/M)%C; int b = id/(M*C);
  dst[id] = src[((size_t)b*C + c)*Nsrc + idx[(size_t)b*M + m]];
}

// ---------------------------------------------------------------------------
extern "C" void kernel_launch(void* const* d_in, const int* in_sizes, int n_in,
                              void* d_out, int out_size, void* d_ws, size_t ws_size,
                              hipStream_t stream) {
  const float* xyz    = (const float*)d_in[0];
  const float* stem_w = (const float*)d_in[1];
  const float* stem_b = (const float*)d_in[2];
  const float* w1 = (const float*)d_in[3];
  const float* g1 = (const float*)d_in[4];
  const float* b1 = (const float*)d_in[5];
  const float* w2 = (const float*)d_in[6];
  const float* g2 = (const float*)d_in[7];
  const float* b2 = (const float*)d_in[8];
  const float* w3 = (const float*)d_in[9];
  const float* g3 = (const float*)d_in[10];
  const float* b3 = (const float*)d_in[11];
  const float* w4 = (const float*)d_in[12];
  const float* g4 = (const float*)d_in[13];
  const float* b4 = (const float*)d_in[14];

  float* out = (float*)d_out;
  float* P0o  = out + 0;
  float* F0a  = out + 49152;
  float* P1o  = out + 573440;
  float* F1a  = out + 585728;
  float* P2o  = out + 847872;
  float* F2a  = out + 850944;

  char* ws = (char*)d_ws;
  float* F0     = (float*)(ws + 0);
  float* pre    = (float*)(ws + 524288);
  float* part_d = (float*)(ws + 524288);
  int*   part_i = (int*)  (ws + 524288 + 16777216);
  int*   idxk   = (int*)  (ws + 34078720);
  double* gsum  = (double*)(ws + 35127296);
  int*   idx1   = (int*)  (ws + 35127552);
  int*   idx2   = (int*)  (ws + 35143936);
  float* F1sk   = (float*)(ws + 35148032);
  float* F2sk   = (float*)(ws + 35672320);
  float* F2mid  = (float*)(ws + 35934464);

  size_t smem_c1 = (size_t)(32*20  + 16*20 )*4;   // CIN=8  -> PAD=20
  size_t smem_c2 = (size_t)(64*68  + 16*68 )*4;   // CIN=32 -> PAD=68
  size_t smem_c3 = (size_t)(64*132 + 16*132)*4;   // CIN=64 -> PAD=132
  size_t smem_c4 = (size_t)(128*132+ 16*132)*4;   // CIN=64, COUT=128
  size_t smem_f1 = (size_t)8192*4 + 512;
  size_t smem_f2 = (size_t)2048*4 + 512;

  hipMemcpyAsync(P0o, xyz, (size_t)49152*4, hipMemcpyDeviceToDevice, stream);
  stem_kernel<<<(2*8192)/256, 256, 0, stream>>>(xyz, stem_w, stem_b, F0, 8192);

  // ---- stage 1
  knn_kernel<<<dim3(16384/256, 16), 256, 0, stream>>>(xyz, xyz, part_d, part_i, 8192, 8192, 512, 16384);
  knn_merge <<<16384/256, 256, 0, stream>>>(part_d, part_i, idxk, 256, 16384);
  edge_conv_pre<8,32><<<dim3(8192,2), 512, smem_c1, stream>>>(F0, F0, idxk, w1, pre, 8192, 8192);
  hipMemsetAsync(gsum, 0, 256, stream);
  gn_reduce<<<dim3(8,8,2), 256, 0, stream>>>(pre, gsum, 4*8192*16);
  gn_act_max<32><<<(2*32*8192)/256, 256, 0, stream>>>(pre, gsum, g1, b1, F0a, 8192);

  // ---- FPS 8192 -> 2048
  fps_kernel<16,512,2048><<<2, 512, smem_f1, stream>>>(xyz, idx1);
  gather_kernel<<<(2*3*2048)/256, 256, 0, stream>>>(P1o, xyz, idx1, 3, 8192, 2048);
  gather_kernel<<<(2*32*2048)/256, 256, 0, stream>>>(F1sk, F0a, idx1, 32, 8192, 2048);

  // ---- stage 2
  knn_kernel<<<dim3(4096/256, 16), 256, 0, stream>>>(P1o, xyz, part_d, part_i, 2048, 8192, 512, 4096);
  knn_merge <<<4096/256, 256, 0, stream>>>(part_d, part_i, idxk, 256, 4096);
  edge_conv_pre<32,64><<<dim3(2048,2), 1024, smem_c2, stream>>>(F0a, F1sk, idxk, w2, pre, 2048, 8192);
  hipMemsetAsync(gsum, 0, 256, stream);
  gn_reduce<<<dim3(4,8,2), 256, 0, stream>>>(pre, gsum, 8*2048*16);
  gn_act_max<64><<<(2*64*2048)/256, 256, 0, stream>>>(pre, gsum, g2, b2, F1a, 2048);

  // ---- FPS 2048 -> 512
  fps_kernel<4,512,512><<<2, 512, smem_f2, stream>>>(P1o, idx2);
  gather_kernel<<<(2*3*512)/256, 256, 0, stream>>>(P2o, P1o, idx2, 3, 2048, 512);
  gather_kernel<<<(2*64*512)/256, 256, 0, stream>>>(F2sk, F1a, idx2, 64, 2048, 512);

  // ---- stage 3
  knn_kernel<<<dim3(1024/256, 8), 256, 0, stream>>>(P2o, P1o, part_d, part_i, 512, 2048, 256, 1024);
  knn_merge <<<1024/256, 256, 0, stream>>>(part_d, part_i, idxk, 128, 1024);
  edge_conv_pre<64,64><<<dim3(512,2), 1024, smem_c3, stream>>>(F1a, F2sk, idxk, w3, pre, 512, 2048);
  hipMemsetAsync(gsum, 0, 256, stream);
  gn_reduce<<<dim3(1,8,2), 256, 0, stream>>>(pre, gsum, 8*512*16);
  gn_act_max<64><<<(2*64*512)/256, 256, 0, stream>>>(pre, gsum, g3, b3, F2mid, 512);

  // ---- stage 4 (same knn idx)
  edge_conv_pre<64,128><<<dim3(512,2), 1024, smem_c4, stream>>>(F1a, F2mid, idxk, w4, pre, 512, 2048);
  hipMemsetAsync(gsum, 0, 256, stream);
  gn_reduce<<<dim3(2,8,2), 256, 0, stream>>>(pre, gsum, 16*512*16);
  gn_act_max<128><<<(2*128*512)/256, 256, 0, stream>>>(pre, gsum, g4, b4, F2a, 512);

  (void)in_sizes; (void)n_in; (void)out_size; (void)ws_size;
}

// Round 5
// 4596.876 us; speedup vs baseline: 1.0129x; 1.0129x over previous
//
#include <hip/hip_runtime.h>
#include <math.h>

typedef unsigned long long ull;

// ---------------------------------------------------------------------------
// stem: F0[b,o,n] = stem_w[o,:] . xyz[b,:,n] + stem_b[o]
// ---------------------------------------------------------------------------
__global__ __launch_bounds__(256) void stem_kernel(const float* __restrict__ xyz,
    const float* __restrict__ w, const float* __restrict__ bias,
    float* __restrict__ F0, int N){
  int id = blockIdx.x*256 + threadIdx.x;
  int n = id % N; int b = id / N;
  float x = xyz[((size_t)b*3+0)*N+n];
  float y = xyz[((size_t)b*3+1)*N+n];
  float z = xyz[((size_t)b*3+2)*N+n];
  #pragma unroll
  for (int o=0;o<8;o++){
    float v = fmaf(w[o*3+0],x, fmaf(w[o*3+1],y, fmaf(w[o*3+2],z, bias[o])));
    F0[((size_t)b*8+o)*N+n] = v;
  }
}

// ---------------------------------------------------------------------------
// KNN: per-thread top-16 over a candidate split; partials stored TRANSPOSED
// (row e = s*16+u, col qg) so both write and merge-read are coalesced.
// Distance mirrors reference: (qq + pp) - 2*dot, non-contracted IEEE ops.
// ---------------------------------------------------------------------------
__global__ __launch_bounds__(256) void knn_kernel(
    const float* __restrict__ Pq, const float* __restrict__ Pp,
    float* __restrict__ part_d, int* __restrict__ part_i,
    int Nq, int Np, int CAND, int total){
  __shared__ float4 tile[256];
  int qg = blockIdx.x*256 + threadIdx.x;
  int b  = qg / Nq, qn = qg % Nq;
  int s  = blockIdx.y;
  const float* Pqb = Pq + (size_t)b*3*Nq;
  const float* Ppb = Pp + (size_t)b*3*Np;
  float qx = Pqb[qn], qy = Pqb[Nq+qn], qz = Pqb[2*Nq+qn];
  float qq = __fadd_rn(__fadd_rn(__fmul_rn(qx,qx),__fmul_rn(qy,qy)),__fmul_rn(qz,qz));

  float dl[16]; int il[16];
  #pragma unroll
  for (int u=0;u<16;u++){ dl[u]=INFINITY; il[u]=-1; }
  float maxd = INFINITY; int maxslot = 0;

  int c0 = s*CAND;
  for (int tb=0; tb<CAND; tb+=256){
    int p = c0 + tb + threadIdx.x;
    float px = Ppb[p], py = Ppb[Np+p], pz = Ppb[2*Np+p];
    float pp = __fadd_rn(__fadd_rn(__fmul_rn(px,px),__fmul_rn(py,py)),__fmul_rn(pz,pz));
    __syncthreads();
    tile[threadIdx.x] = make_float4(px,py,pz,pp);
    __syncthreads();
    for (int j=0;j<256;j++){
      float4 c = tile[j];
      float dot = __fadd_rn(__fadd_rn(__fmul_rn(qx,c.x),__fmul_rn(qy,c.y)),__fmul_rn(qz,c.z));
      float dc  = __fsub_rn(__fadd_rn(qq,c.w), __fmul_rn(2.0f,dot));
      if (dc < maxd){
        int pidx = c0 + tb + j;
        #pragma unroll
        for (int u=0;u<16;u++){ bool sel=(maxslot==u); dl[u]=sel?dc:dl[u]; il[u]=sel?pidx:il[u]; }
        maxd = dl[0]; maxslot = 0;
        #pragma unroll
        for (int u=1;u<16;u++){ bool g=(dl[u]>maxd); maxd=g?dl[u]:maxd; maxslot=g?u:maxslot; }
      }
    }
  }
  #pragma unroll
  for (int u=0;u<16;u++){
    size_t row = (size_t)(s*16+u);
    part_d[row*total + qg] = dl[u];
    part_i[row*total + qg] = il[u];
  }
}

// merge transposed partials -> final 16 (lex (d, idx) smallest); coalesced reads
__global__ __launch_bounds__(256) void knn_merge(const float* __restrict__ part_d,
    const int* __restrict__ part_i, int* __restrict__ idxk, int rows, int total){
  int qg = blockIdx.x*256 + threadIdx.x;
  if (qg >= total) return;
  float dl[16]; int il[16];
  #pragma unroll
  for (int u=0;u<16;u++){ dl[u]=INFINITY; il[u]=0x7fffffff; }
  float maxd = INFINITY; int maxi = 0x7fffffff; int maxslot = 0;
  for (int e=0;e<rows;e++){
    float d = part_d[(size_t)e*total + qg];
    int  ii = part_i[(size_t)e*total + qg];
    bool better = (d < maxd) || (d == maxd && ii < maxi);
    if (better){
      #pragma unroll
      for (int u=0;u<16;u++){ bool sel=(maxslot==u); dl[u]=sel?d:dl[u]; il[u]=sel?ii:il[u]; }
      maxd = dl[0]; maxi = il[0]; maxslot = 0;
      #pragma unroll
      for (int u=1;u<16;u++){
        bool g = (dl[u]>maxd) || (dl[u]==maxd && il[u]>maxi);
        maxd=g?dl[u]:maxd; maxi=g?il[u]:maxi; maxslot=g?u:maxslot;
      }
    }
  }
  #pragma unroll
  for (int u=0;u<16;u++) idxk[(size_t)qg*16+u] = il[u];
}

// ---------------------------------------------------------------------------
// EdgeConv pre-activation
// ---------------------------------------------------------------------------
template<int CIN, int COUT>
__global__ __launch_bounds__(1024) void edge_conv_pre(
    const float* __restrict__ Fk, const float* __restrict__ Fi,
    const int* __restrict__ idx, const float* __restrict__ W,
    float* __restrict__ pre, int Nq, int Np){
  constexpr int C2  = 2*CIN;
  constexpr int PAD = C2 + 4;
  constexpr int TO  = (COUT <= 64) ? COUT : 64;
  constexpr int OP  = COUT / TO;
  extern __shared__ float sm[];
  float* Wl = sm;
  float* Pl = sm + COUT*PAD;
  int t = threadIdx.x;
  int n = blockIdx.x, b = blockIdx.y;
  for (int e=t; e<COUT*C2; e += blockDim.x){
    int o=e/C2, c=e%C2; Wl[o*PAD+c] = W[e];
  }
  const int* idxn = idx + ((size_t)b*Nq + n)*16;
  for (int e=t; e<16*C2; e += blockDim.x){
    int k = e/C2, c = e%C2;
    int cc = (c < CIN) ? c : (c-CIN);
    float fi = Fi[((size_t)b*CIN + cc)*Nq + n];
    float v;
    if (c < CIN){ int nb = idxn[k]; v = Fk[((size_t)b*CIN + c)*Np + nb] - fi; }
    else v = fi;
    Pl[k*PAD+c] = v;
  }
  __syncthreads();
  int k = t & 15, o0 = t >> 4;
  #pragma unroll
  for (int op=0; op<OP; op++){
    int o = o0 + op*TO;
    float acc = 0.f;
    #pragma unroll
    for (int c=0;c<C2;c+=4){
      float4 wv = *(const float4*)&Wl[o*PAD+c];
      float4 pv = *(const float4*)&Pl[k*PAD+c];
      acc = fmaf(wv.x,pv.x,acc); acc = fmaf(wv.y,pv.y,acc);
      acc = fmaf(wv.z,pv.z,acc); acc = fmaf(wv.w,pv.w,acc);
    }
    pre[(((size_t)b*COUT + o)*Nq + n)*16 + k] = acc;
  }
}

// GroupNorm stats
__global__ __launch_bounds__(256) void gn_reduce(const float* __restrict__ pre,
    double* __restrict__ gsum, int slabLen){
  int b = blockIdx.z, g = blockIdx.y;
  size_t base = ((size_t)(b*8+g))*slabLen;
  int chunkLen = slabLen / gridDim.x;
  const float* p = pre + base + (size_t)blockIdx.x*chunkLen;
  double s=0.0, sq=0.0;
  for (int i = threadIdx.x*4; i < chunkLen; i += 1024){
    float4 v = *(const float4*)(p+i);
    s += (double)v.x; sq = fma((double)v.x,(double)v.x,sq);
    s += (double)v.y; sq = fma((double)v.y,(double)v.y,sq);
    s += (double)v.z; sq = fma((double)v.z,(double)v.z,sq);
    s += (double)v.w; sq = fma((double)v.w,(double)v.w,sq);
  }
  #pragma unroll
  for (int off=32; off>=1; off>>=1){ s += __shfl_down(s, off); sq += __shfl_down(sq, off); }
  __shared__ double ls[4], lq[4];
  int wid = threadIdx.x>>6;
  if ((threadIdx.x&63)==0){ ls[wid]=s; lq[wid]=sq; }
  __syncthreads();
  if (threadIdx.x==0){
    double S=ls[0]+ls[1]+ls[2]+ls[3], Q=lq[0]+lq[1]+lq[2]+lq[3];
    atomicAdd(&gsum[(b*8+g)*2],   S);
    atomicAdd(&gsum[(b*8+g)*2+1], Q);
  }
}

// normalize + affine + relu + max over K
template<int COUT>
__global__ __launch_bounds__(256) void gn_act_max(const float* __restrict__ pre,
    const double* __restrict__ gsum, const float* __restrict__ gamma,
    const float* __restrict__ beta, float* __restrict__ outF, int Nq){
  int id = blockIdx.x*256 + threadIdx.x;
  int o = (id/Nq)%COUT; int b = id/(Nq*COUT);
  int g = o/(COUT/8);
  double s = gsum[(b*8+g)*2], sq = gsum[(b*8+g)*2+1];
  double cnt = (double)(COUT/8)*Nq*16.0;
  double mu  = s/cnt;
  double var = sq/cnt - mu*mu;
  float muf=(float)mu, rstd=(float)(1.0/sqrt(var+1e-5));
  float ga=gamma[o], be=beta[o];
  const float4* p = (const float4*)(pre + (size_t)id*16);
  float m = 0.f;
  #pragma unroll
  for (int q=0;q<4;q++){
    float4 v = p[q];
    m = fmaxf(m, fmaf((v.x-muf)*rstd, ga, be));
    m = fmaxf(m, fmaf((v.y-muf)*rstd, ga, be));
    m = fmaxf(m, fmaf((v.z-muf)*rstd, ga, be));
    m = fmaxf(m, fmaf((v.w-muf)*rstd, ga, be));
  }
  outF[id] = m;
}

// ---------------------------------------------------------------------------
// FPS v4: round-2 validated reduce structure (DPP wave-max + ballot + 1
// barrier, double-buffered wave keys), but BLK=1024 / PPT small so ALL
// per-thread state (dist, coords) stays in REGISTERS (no scratch spill).
// Contiguous ownership (thread t owns [t*PPT, t*PPT+PPT)) so lowest-lane /
// lowest-wave tie-break == reference first-occurrence argmax.
// Arithmetic identical to reference (non-contracted sub/mul/add, fminf).
// ---------------------------------------------------------------------------
template<int CTRL>
__device__ __forceinline__ float dpp_maxf(float x){
  int y = __builtin_amdgcn_update_dpp(0, __float_as_int(x), CTRL, 0xf, 0xf, true);
  return fmaxf(x, __int_as_float(y));
}

template<int PPT, int BLK, int M>
__global__ __launch_bounds__(BLK) void fps_kernel(const float* __restrict__ P,
    int* __restrict__ idx_out){
  constexpr int N  = PPT*BLK;
  constexpr int NW = BLK/64;
  extern __shared__ __align__(16) float sm[];
  float* lx = sm; float* ly = sm+N; float* lz = sm+2*N;
  ull* wk = (ull*)(sm + 3*N);               // 2*NW double-buffered keys
  int b = blockIdx.x, t = threadIdx.x;
  const float* Pb = P + (size_t)b*3*N;
  // coalesced global -> LDS
  for (int i=t; i<N; i+=BLK){ lx[i]=Pb[i]; ly[i]=Pb[N+i]; lz[i]=Pb[2*N+i]; }
  __syncthreads();
  // register-resident owned points (contiguous run of PPT)
  float px[PPT], py[PPT], pz[PPT], dist[PPT];
  #pragma unroll
  for (int j=0;j<PPT;j++){ int p=t*PPT+j; px[j]=lx[p]; py[j]=ly[p]; pz[j]=lz[p]; }
  float sx = lx[0], sy = ly[0], sz = lz[0];
  float bd = -1.f; int bj = 0;
  #pragma unroll
  for (int j=0;j<PPT;j++){
    float dx=__fsub_rn(px[j],sx), dy=__fsub_rn(py[j],sy), dz=__fsub_rn(pz[j],sz);
    float dd=__fadd_rn(__fadd_rn(__fmul_rn(dx,dx),__fmul_rn(dy,dy)),__fmul_rn(dz,dz));
    dist[j]=dd;
    bool c = dd > bd; bd = c?dd:bd; bj = c?j:bj;
  }
  int pbest = t*PPT + bj;
  if (t==0) idx_out[(size_t)b*M] = 0;
  int wid = t>>6, lane = t&63, par = 0;
  for (int i=1;i<M;i++){
    // wave max via DPP chain (full-wave max lands in lane 63)
    float r = bd;
    r = dpp_maxf<0x111>(r); r = dpp_maxf<0x112>(r);
    r = dpp_maxf<0x114>(r); r = dpp_maxf<0x118>(r);
    r = dpp_maxf<0x142>(r); r = dpp_maxf<0x143>(r);
    float wmax = __int_as_float(__builtin_amdgcn_readlane(__float_as_int(r), 63));
    ull msk = __ballot(bd == wmax);
    int srcl = __ffsll(msk) - 1;            // lowest lane == lowest owned index
    int wp = __builtin_amdgcn_readlane(pbest, srcl);
    if (lane==0)
      wk[par*NW + wid] = ((ull)__float_as_uint(wmax)<<32)
                       | (unsigned)(~(unsigned)wp);
    __syncthreads();
    ull best = wk[par*NW];
    #pragma unroll
    for (int w=1;w<NW;w++){ ull o = wk[par*NW+w]; best = (o>best)?o:best; }
    unsigned widx = ~(unsigned)best;
    if (t==0) idx_out[(size_t)b*M + i] = (int)widx;
    float nsx = lx[widx], nsy = ly[widx], nsz = lz[widx];
    par ^= 1;
    // register-only min-update + fused argmax scan
    float nbd = -1.f; int nbj = 0;
    #pragma unroll
    for (int j=0;j<PPT;j++){
      float dx=__fsub_rn(px[j],nsx), dy=__fsub_rn(py[j],nsy), dz=__fsub_rn(pz[j],nsz);
      float dd=__fadd_rn(__fadd_rn(__fmul_rn(dx,dx),__fmul_rn(dy,dy)),__fmul_rn(dz,dz));
      float nd = fminf(dist[j], dd);
      dist[j] = nd;
      bool c = nd > nbd; nbd = c?nd:nbd; nbj = c?j:nbj;
    }
    bd = nbd; pbest = t*PPT + nbj;
  }
}

// gather
__global__ __launch_bounds__(256) void gather_kernel(float* __restrict__ dst,
    const float* __restrict__ src, const int* __restrict__ idx,
    int C, int Nsrc, int M){
  int id = blockIdx.x*256 + threadIdx.x;
  int m = id % M; int c = (id/M)%C; int b = id/(M*C);
  dst[id] = src[((size_t)b*C + c)*Nsrc + idx[(size_t)b*M + m]];
}

// ---------------------------------------------------------------------------
extern "C" void kernel_launch(void* const* d_in, const int* in_sizes, int n_in,
                              void* d_out, int out_size, void* d_ws, size_t ws_size,
                              hipStream_t stream) {
  const float* xyz    = (const float*)d_in[0];
  const float* stem_w = (const float*)d_in[1];
  const float* stem_b = (const float*)d_in[2];
  const float* w1 = (const float*)d_in[3];
  const float* g1 = (const float*)d_in[4];
  const float* b1 = (const float*)d_in[5];
  const float* w2 = (const float*)d_in[6];
  const float* g2 = (const float*)d_in[7];
  const float* b2 = (const float*)d_in[8];
  const float* w3 = (const float*)d_in[9];
  const float* g3 = (const float*)d_in[10];
  const float* b3 = (const float*)d_in[11];
  const float* w4 = (const float*)d_in[12];
  const float* g4 = (const float*)d_in[13];
  const float* b4 = (const float*)d_in[14];

  float* out = (float*)d_out;
  float* P0o  = out + 0;
  float* F0a  = out + 49152;
  float* P1o  = out + 573440;
  float* F1a  = out + 585728;
  float* P2o  = out + 847872;
  float* F2a  = out + 850944;

  char* ws = (char*)d_ws;
  float* F0     = (float*)(ws + 0);
  float* pre    = (float*)(ws + 524288);
  float* part_d = (float*)(ws + 524288);
  int*   part_i = (int*)  (ws + 524288 + 16777216);
  int*   idxk   = (int*)  (ws + 34078720);
  double* gsum  = (double*)(ws + 35127296);
  int*   idx1   = (int*)  (ws + 35127552);
  int*   idx2   = (int*)  (ws + 35143936);
  float* F1sk   = (float*)(ws + 35148032);
  float* F2sk   = (float*)(ws + 35672320);
  float* F2mid  = (float*)(ws + 35934464);

  size_t smem_c1 = (size_t)(32*20  + 16*20 )*4;   // CIN=8  -> PAD=20
  size_t smem_c2 = (size_t)(64*68  + 16*68 )*4;   // CIN=32 -> PAD=68
  size_t smem_c3 = (size_t)(64*132 + 16*132)*4;   // CIN=64 -> PAD=132
  size_t smem_c4 = (size_t)(128*132+ 16*132)*4;   // CIN=64, COUT=128
  size_t smem_f1 = (size_t)3*8192*4 + 256;        // 96 KiB coords + keys
  size_t smem_f2 = (size_t)3*2048*4 + 256;

  hipMemcpyAsync(P0o, xyz, (size_t)49152*4, hipMemcpyDeviceToDevice, stream);
  stem_kernel<<<(2*8192)/256, 256, 0, stream>>>(xyz, stem_w, stem_b, F0, 8192);

  // ---- stage 1
  knn_kernel<<<dim3(16384/256, 16), 256, 0, stream>>>(xyz, xyz, part_d, part_i, 8192, 8192, 512, 16384);
  knn_merge <<<16384/256, 256, 0, stream>>>(part_d, part_i, idxk, 256, 16384);
  edge_conv_pre<8,32><<<dim3(8192,2), 512, smem_c1, stream>>>(F0, F0, idxk, w1, pre, 8192, 8192);
  hipMemsetAsync(gsum, 0, 256, stream);
  gn_reduce<<<dim3(8,8,2), 256, 0, stream>>>(pre, gsum, 4*8192*16);
  gn_act_max<32><<<(2*32*8192)/256, 256, 0, stream>>>(pre, gsum, g1, b1, F0a, 8192);

  // ---- FPS 8192 -> 2048
  fps_kernel<8,1024,2048><<<2, 1024, smem_f1, stream>>>(xyz, idx1);
  gather_kernel<<<(2*3*2048)/256, 256, 0, stream>>>(P1o, xyz, idx1, 3, 8192, 2048);
  gather_kernel<<<(2*32*2048)/256, 256, 0, stream>>>(F1sk, F0a, idx1, 32, 8192, 2048);

  // ---- stage 2
  knn_kernel<<<dim3(4096/256, 16), 256, 0, stream>>>(P1o, xyz, part_d, part_i, 2048, 8192, 512, 4096);
  knn_merge <<<4096/256, 256, 0, stream>>>(part_d, part_i, idxk, 256, 4096);
  edge_conv_pre<32,64><<<dim3(2048,2), 1024, smem_c2, stream>>>(F0a, F1sk, idxk, w2, pre, 2048, 8192);
  hipMemsetAsync(gsum, 0, 256, stream);
  gn_reduce<<<dim3(4,8,2), 256, 0, stream>>>(pre, gsum, 8*2048*16);
  gn_act_max<64><<<(2*64*2048)/256, 256, 0, stream>>>(pre, gsum, g2, b2, F1a, 2048);

  // ---- FPS 2048 -> 512
  fps_kernel<2,1024,512><<<2, 1024, smem_f2, stream>>>(P1o, idx2);
  gather_kernel<<<(2*3*512)/256, 256, 0, stream>>>(P2o, P1o, idx2, 3, 2048, 512);
  gather_kernel<<<(2*64*512)/256, 256, 0, stream>>>(F2sk, F1a, idx2, 64, 2048, 512);

  // ---- stage 3
  knn_kernel<<<dim3(1024/256, 8), 256, 0, stream>>>(P2o, P1o, part_d, part_i, 512, 2048, 256, 1024);
  knn_merge <<<1024/256, 256, 0, stream>>>(part_d, part_i, idxk, 128, 1024);
  edge_conv_pre<64,64><<<dim3(512,2), 1024, smem_c3, stream>>>(F1a, F2sk, idxk, w3, pre, 512, 2048);
  hipMemsetAsync(gsum, 0, 256, stream);
  gn_reduce<<<dim3(1,8,2), 256, 0, stream>>>(pre, gsum, 8*512*16);
  gn_act_max<64><<<(2*64*512)/256, 256, 0, stream>>>(pre, gsum, g3, b3, F2mid, 512);

  // ---- stage 4 (same knn idx)
  edge_conv_pre<64,128><<<dim3(512,2), 1024, smem_c4, stream>>>(F1a, F2mid, idxk, w4, pre, 512, 2048);
  hipMemsetAsync(gsum, 0, 256, stream);
  gn_reduce<<<dim3(2,8,2), 256, 0, stream>>>(pre, gsum, 16*512*16);
  gn_act_max<128><<<(2*128*512)/256, 256, 0, stream>>>(pre, gsum, g4, b4, F2a, 512);

  (void)in_sizes; (void)n_in; (void)out_size; (void)ws_size;
}

// Round 6
// 4594.493 us; speedup vs baseline: 1.0134x; 1.0005x over previous
//
#include <hip/hip_runtime.h>
#include <math.h>

typedef unsigned long long ull;

// ---------------------------------------------------------------------------
// stem: F0[b,o,n] = stem_w[o,:] . xyz[b,:,n] + stem_b[o]
// ---------------------------------------------------------------------------
__global__ __launch_bounds__(256) void stem_kernel(const float* __restrict__ xyz,
    const float* __restrict__ w, const float* __restrict__ bias,
    float* __restrict__ F0, int N){
  int id = blockIdx.x*256 + threadIdx.x;
  int n = id % N; int b = id / N;
  float x = xyz[((size_t)b*3+0)*N+n];
  float y = xyz[((size_t)b*3+1)*N+n];
  float z = xyz[((size_t)b*3+2)*N+n];
  #pragma unroll
  for (int o=0;o<8;o++){
    float v = fmaf(w[o*3+0],x, fmaf(w[o*3+1],y, fmaf(w[o*3+2],z, bias[o])));
    F0[((size_t)b*8+o)*N+n] = v;
  }
}

// ---------------------------------------------------------------------------
// KNN: per-thread top-16 over a candidate split; partials stored TRANSPOSED
// (row e = s*16+u, col qg) so both write and merge-read are coalesced.
// Distance mirrors reference: (qq + pp) - 2*dot, non-contracted IEEE ops.
// ---------------------------------------------------------------------------
__global__ __launch_bounds__(256) void knn_kernel(
    const float* __restrict__ Pq, const float* __restrict__ Pp,
    float* __restrict__ part_d, int* __restrict__ part_i,
    int Nq, int Np, int CAND, int total){
  __shared__ float4 tile[256];
  int qg = blockIdx.x*256 + threadIdx.x;
  int b  = qg / Nq, qn = qg % Nq;
  int s  = blockIdx.y;
  const float* Pqb = Pq + (size_t)b*3*Nq;
  const float* Ppb = Pp + (size_t)b*3*Np;
  float qx = Pqb[qn], qy = Pqb[Nq+qn], qz = Pqb[2*Nq+qn];
  float qq = __fadd_rn(__fadd_rn(__fmul_rn(qx,qx),__fmul_rn(qy,qy)),__fmul_rn(qz,qz));

  float dl[16]; int il[16];
  #pragma unroll
  for (int u=0;u<16;u++){ dl[u]=INFINITY; il[u]=-1; }
  float maxd = INFINITY; int maxslot = 0;

  int c0 = s*CAND;
  for (int tb=0; tb<CAND; tb+=256){
    int p = c0 + tb + threadIdx.x;
    float px = Ppb[p], py = Ppb[Np+p], pz = Ppb[2*Np+p];
    float pp = __fadd_rn(__fadd_rn(__fmul_rn(px,px),__fmul_rn(py,py)),__fmul_rn(pz,pz));
    __syncthreads();
    tile[threadIdx.x] = make_float4(px,py,pz,pp);
    __syncthreads();
    for (int j=0;j<256;j++){
      float4 c = tile[j];
      float dot = __fadd_rn(__fadd_rn(__fmul_rn(qx,c.x),__fmul_rn(qy,c.y)),__fmul_rn(qz,c.z));
      float dc  = __fsub_rn(__fadd_rn(qq,c.w), __fmul_rn(2.0f,dot));
      if (dc < maxd){
        int pidx = c0 + tb + j;
        #pragma unroll
        for (int u=0;u<16;u++){ bool sel=(maxslot==u); dl[u]=sel?dc:dl[u]; il[u]=sel?pidx:il[u]; }
        maxd = dl[0]; maxslot = 0;
        #pragma unroll
        for (int u=1;u<16;u++){ bool g=(dl[u]>maxd); maxd=g?dl[u]:maxd; maxslot=g?u:maxslot; }
      }
    }
  }
  #pragma unroll
  for (int u=0;u<16;u++){
    size_t row = (size_t)(s*16+u);
    part_d[row*total + qg] = dl[u];
    part_i[row*total + qg] = il[u];
  }
}

// merge transposed partials -> final 16 (lex (d, idx) smallest); coalesced reads
__global__ __launch_bounds__(256) void knn_merge(const float* __restrict__ part_d,
    const int* __restrict__ part_i, int* __restrict__ idxk, int rows, int total){
  int qg = blockIdx.x*256 + threadIdx.x;
  if (qg >= total) return;
  float dl[16]; int il[16];
  #pragma unroll
  for (int u=0;u<16;u++){ dl[u]=INFINITY; il[u]=0x7fffffff; }
  float maxd = INFINITY; int maxi = 0x7fffffff; int maxslot = 0;
  for (int e=0;e<rows;e++){
    float d = part_d[(size_t)e*total + qg];
    int  ii = part_i[(size_t)e*total + qg];
    bool better = (d < maxd) || (d == maxd && ii < maxi);
    if (better){
      #pragma unroll
      for (int u=0;u<16;u++){ bool sel=(maxslot==u); dl[u]=sel?d:dl[u]; il[u]=sel?ii:il[u]; }
      maxd = dl[0]; maxi = il[0]; maxslot = 0;
      #pragma unroll
      for (int u=1;u<16;u++){
        bool g = (dl[u]>maxd) || (dl[u]==maxd && il[u]>maxi);
        maxd=g?dl[u]:maxd; maxi=g?il[u]:maxi; maxslot=g?u:maxslot;
      }
    }
  }
  #pragma unroll
  for (int u=0;u<16;u++) idxk[(size_t)qg*16+u] = il[u];
}

// ---------------------------------------------------------------------------
// EdgeConv pre-activation
// ---------------------------------------------------------------------------
template<int CIN, int COUT>
__global__ __launch_bounds__(1024) void edge_conv_pre(
    const float* __restrict__ Fk, const float* __restrict__ Fi,
    const int* __restrict__ idx, const float* __restrict__ W,
    float* __restrict__ pre, int Nq, int Np){
  constexpr int C2  = 2*CIN;
  constexpr int PAD = C2 + 4;
  constexpr int TO  = (COUT <= 64) ? COUT : 64;
  constexpr int OP  = COUT / TO;
  extern __shared__ float sm[];
  float* Wl = sm;
  float* Pl = sm + COUT*PAD;
  int t = threadIdx.x;
  int n = blockIdx.x, b = blockIdx.y;
  for (int e=t; e<COUT*C2; e += blockDim.x){
    int o=e/C2, c=e%C2; Wl[o*PAD+c] = W[e];
  }
  const int* idxn = idx + ((size_t)b*Nq + n)*16;
  for (int e=t; e<16*C2; e += blockDim.x){
    int k = e/C2, c = e%C2;
    int cc = (c < CIN) ? c : (c-CIN);
    float fi = Fi[((size_t)b*CIN + cc)*Nq + n];
    float v;
    if (c < CIN){ int nb = idxn[k]; v = Fk[((size_t)b*CIN + c)*Np + nb] - fi; }
    else v = fi;
    Pl[k*PAD+c] = v;
  }
  __syncthreads();
  int k = t & 15, o0 = t >> 4;
  #pragma unroll
  for (int op=0; op<OP; op++){
    int o = o0 + op*TO;
    float acc = 0.f;
    #pragma unroll
    for (int c=0;c<C2;c+=4){
      float4 wv = *(const float4*)&Wl[o*PAD+c];
      float4 pv = *(const float4*)&Pl[k*PAD+c];
      acc = fmaf(wv.x,pv.x,acc); acc = fmaf(wv.y,pv.y,acc);
      acc = fmaf(wv.z,pv.z,acc); acc = fmaf(wv.w,pv.w,acc);
    }
    pre[(((size_t)b*COUT + o)*Nq + n)*16 + k] = acc;
  }
}

// GroupNorm stats
__global__ __launch_bounds__(256) void gn_reduce(const float* __restrict__ pre,
    double* __restrict__ gsum, int slabLen){
  int b = blockIdx.z, g = blockIdx.y;
  size_t base = ((size_t)(b*8+g))*slabLen;
  int chunkLen = slabLen / gridDim.x;
  const float* p = pre + base + (size_t)blockIdx.x*chunkLen;
  double s=0.0, sq=0.0;
  for (int i = threadIdx.x*4; i < chunkLen; i += 1024){
    float4 v = *(const float4*)(p+i);
    s += (double)v.x; sq = fma((double)v.x,(double)v.x,sq);
    s += (double)v.y; sq = fma((double)v.y,(double)v.y,sq);
    s += (double)v.z; sq = fma((double)v.z,(double)v.z,sq);
    s += (double)v.w; sq = fma((double)v.w,(double)v.w,sq);
  }
  #pragma unroll
  for (int off=32; off>=1; off>>=1){ s += __shfl_down(s, off); sq += __shfl_down(sq, off); }
  __shared__ double ls[4], lq[4];
  int wid = threadIdx.x>>6;
  if ((threadIdx.x&63)==0){ ls[wid]=s; lq[wid]=sq; }
  __syncthreads();
  if (threadIdx.x==0){
    double S=ls[0]+ls[1]+ls[2]+ls[3], Q=lq[0]+lq[1]+lq[2]+lq[3];
    atomicAdd(&gsum[(b*8+g)*2],   S);
    atomicAdd(&gsum[(b*8+g)*2+1], Q);
  }
}

// normalize + affine + relu + max over K
template<int COUT>
__global__ __launch_bounds__(256) void gn_act_max(const float* __restrict__ pre,
    const double* __restrict__ gsum, const float* __restrict__ gamma,
    const float* __restrict__ beta, float* __restrict__ outF, int Nq){
  int id = blockIdx.x*256 + threadIdx.x;
  int o = (id/Nq)%COUT; int b = id/(Nq*COUT);
  int g = o/(COUT/8);
  double s = gsum[(b*8+g)*2], sq = gsum[(b*8+g)*2+1];
  double cnt = (double)(COUT/8)*Nq*16.0;
  double mu  = s/cnt;
  double var = sq/cnt - mu*mu;
  float muf=(float)mu, rstd=(float)(1.0/sqrt(var+1e-5));
  float ga=gamma[o], be=beta[o];
  const float4* p = (const float4*)(pre + (size_t)id*16);
  float m = 0.f;
  #pragma unroll
  for (int q=0;q<4;q++){
    float4 v = p[q];
    m = fmaxf(m, fmaf((v.x-muf)*rstd, ga, be));
    m = fmaxf(m, fmaf((v.y-muf)*rstd, ga, be));
    m = fmaxf(m, fmaf((v.z-muf)*rstd, ga, be));
    m = fmaxf(m, fmaf((v.w-muf)*rstd, ga, be));
  }
  outF[id] = m;
}

// ---------------------------------------------------------------------------
// FPS v5: v4 structure, but per-thread coords are PINNED into VGPRs via an
// opaque asm touch after the LDS->reg load. Without this, the compiler
// rematerializes px/py/pz from LDS inside the hot loop (24 ds_read_b32 per
// thread per iteration -> LDS-pipe bound; round-5 VGPR_Count=28 was the
// smoking gun). launch_bounds(BLK,4) grants the full 128-VGPR budget (grid
// is only 2 blocks; occupancy is irrelevant).
// Selection semantics identical to the validated round-2 path.
// ---------------------------------------------------------------------------
template<int CTRL>
__device__ __forceinline__ float dpp_maxf(float x){
  int y = __builtin_amdgcn_update_dpp(0, __float_as_int(x), CTRL, 0xf, 0xf, true);
  return fmaxf(x, __int_as_float(y));
}

template<int PPT, int BLK, int M>
__global__ __launch_bounds__(BLK, 4) void fps_kernel(const float* __restrict__ P,
    int* __restrict__ idx_out){
  constexpr int N  = PPT*BLK;
  constexpr int NW = BLK/64;
  extern __shared__ __align__(16) float sm[];
  float* lx = sm; float* ly = sm+N; float* lz = sm+2*N;
  ull* wk = (ull*)(sm + 3*N);               // 2*NW double-buffered keys
  int b = blockIdx.x, t = threadIdx.x;
  const float* Pb = P + (size_t)b*3*N;
  // coalesced global -> LDS
  for (int i=t; i<N; i+=BLK){ lx[i]=Pb[i]; ly[i]=Pb[N+i]; lz[i]=Pb[2*N+i]; }
  __syncthreads();
  // register-resident owned points (contiguous run of PPT)
  float px[PPT], py[PPT], pz[PPT], dist[PPT];
  #pragma unroll
  for (int j=0;j<PPT;j++){ int p=t*PPT+j; px[j]=lx[p]; py[j]=ly[p]; pz[j]=lz[p]; }
  // PIN: make values opaque so the compiler cannot re-read them from LDS
  // inside the iteration loop (forces true register residency).
  #pragma unroll
  for (int j=0;j<PPT;j++){
    asm volatile("" : "+v"(px[j]), "+v"(py[j]), "+v"(pz[j]));
  }
  float sx = lx[0], sy = ly[0], sz = lz[0];
  float bd = -1.f; int bj = 0;
  #pragma unroll
  for (int j=0;j<PPT;j++){
    float dx=__fsub_rn(px[j],sx), dy=__fsub_rn(py[j],sy), dz=__fsub_rn(pz[j],sz);
    float dd=__fadd_rn(__fadd_rn(__fmul_rn(dx,dx),__fmul_rn(dy,dy)),__fmul_rn(dz,dz));
    dist[j]=dd;
    bool c = dd > bd; bd = c?dd:bd; bj = c?j:bj;
  }
  int pbest = t*PPT + bj;
  if (t==0) idx_out[(size_t)b*M] = 0;
  int wid = t>>6, lane = t&63, par = 0;
  for (int i=1;i<M;i++){
    // wave max via DPP chain (full-wave max lands in lane 63)
    float r = bd;
    r = dpp_maxf<0x111>(r); r = dpp_maxf<0x112>(r);
    r = dpp_maxf<0x114>(r); r = dpp_maxf<0x118>(r);
    r = dpp_maxf<0x142>(r); r = dpp_maxf<0x143>(r);
    float wmax = __int_as_float(__builtin_amdgcn_readlane(__float_as_int(r), 63));
    ull msk = __ballot(bd == wmax);
    int srcl = __ffsll(msk) - 1;            // lowest lane == lowest owned index
    int wp = __builtin_amdgcn_readlane(pbest, srcl);
    if (lane==0)
      wk[par*NW + wid] = ((ull)__float_as_uint(wmax)<<32)
                       | (unsigned)(~(unsigned)wp);
    __syncthreads();
    ull best = wk[par*NW];
    #pragma unroll
    for (int w=1;w<NW;w++){ ull o = wk[par*NW+w]; best = (o>best)?o:best; }
    unsigned widx = ~(unsigned)best;
    if (t==0) idx_out[(size_t)b*M + i] = (int)widx;
    float nsx = lx[widx], nsy = ly[widx], nsz = lz[widx];
    par ^= 1;
    // register-only min-update + fused argmax scan
    float nbd = -1.f; int nbj = 0;
    #pragma unroll
    for (int j=0;j<PPT;j++){
      float dx=__fsub_rn(px[j],nsx), dy=__fsub_rn(py[j],nsy), dz=__fsub_rn(pz[j],nsz);
      float dd=__fadd_rn(__fadd_rn(__fmul_rn(dx,dx),__fmul_rn(dy,dy)),__fmul_rn(dz,dz));
      float nd = fminf(dist[j], dd);
      dist[j] = nd;
      bool c = nd > nbd; nbd = c?nd:nbd; nbj = c?j:nbj;
    }
    bd = nbd; pbest = t*PPT + nbj;
  }
}

// gather
__global__ __launch_bounds__(256) void gather_kernel(float* __restrict__ dst,
    const float* __restrict__ src, const int* __restrict__ idx,
    int C, int Nsrc, int M){
  int id = blockIdx.x*256 + threadIdx.x;
  int m = id % M; int c = (id/M)%C; int b = id/(M*C);
  dst[id] = src[((size_t)b*C + c)*Nsrc + idx[(size_t)b*M + m]];
}

// ---------------------------------------------------------------------------
extern "C" void kernel_launch(void* const* d_in, const int* in_sizes, int n_in,
                              void* d_out, int out_size, void* d_ws, size_t ws_size,
                              hipStream_t stream) {
  const float* xyz    = (const float*)d_in[0];
  const float* stem_w = (const float*)d_in[1];
  const float* stem_b = (const float*)d_in[2];
  const float* w1 = (const float*)d_in[3];
  const float* g1 = (const float*)d_in[4];
  const float* b1 = (const float*)d_in[5];
  const float* w2 = (const float*)d_in[6];
  const float* g2 = (const float*)d_in[7];
  const float* b2 = (const float*)d_in[8];
  const float* w3 = (const float*)d_in[9];
  const float* g3 = (const float*)d_in[10];
  const float* b3 = (const float*)d_in[11];
  const float* w4 = (const float*)d_in[12];
  const float* g4 = (const float*)d_in[13];
  const float* b4 = (const float*)d_in[14];

  float* out = (float*)d_out;
  float* P0o  = out + 0;
  float* F0a  = out + 49152;
  float* P1o  = out + 573440;
  float* F1a  = out + 585728;
  float* P2o  = out + 847872;
  float* F2a  = out + 850944;

  char* ws = (char*)d_ws;
  float* F0     = (float*)(ws + 0);
  float* pre    = (float*)(ws + 524288);
  float* part_d = (float*)(ws + 524288);
  int*   part_i = (int*)  (ws + 524288 + 16777216);
  int*   idxk   = (int*)  (ws + 34078720);
  double* gsum  = (double*)(ws + 35127296);
  int*   idx1   = (int*)  (ws + 35127552);
  int*   idx2   = (int*)  (ws + 35143936);
  float* F1sk   = (float*)(ws + 35148032);
  float* F2sk   = (float*)(ws + 35672320);
  float* F2mid  = (float*)(ws + 35934464);

  size_t smem_c1 = (size_t)(32*20  + 16*20 )*4;   // CIN=8  -> PAD=20
  size_t smem_c2 = (size_t)(64*68  + 16*68 )*4;   // CIN=32 -> PAD=68
  size_t smem_c3 = (size_t)(64*132 + 16*132)*4;   // CIN=64 -> PAD=132
  size_t smem_c4 = (size_t)(128*132+ 16*132)*4;   // CIN=64, COUT=128
  size_t smem_f1 = (size_t)3*8192*4 + 256;        // 96 KiB coords + keys
  size_t smem_f2 = (size_t)3*2048*4 + 256;

  hipMemcpyAsync(P0o, xyz, (size_t)49152*4, hipMemcpyDeviceToDevice, stream);
  stem_kernel<<<(2*8192)/256, 256, 0, stream>>>(xyz, stem_w, stem_b, F0, 8192);

  // ---- stage 1
  knn_kernel<<<dim3(16384/256, 16), 256, 0, stream>>>(xyz, xyz, part_d, part_i, 8192, 8192, 512, 16384);
  knn_merge <<<16384/256, 256, 0, stream>>>(part_d, part_i, idxk, 256, 16384);
  edge_conv_pre<8,32><<<dim3(8192,2), 512, smem_c1, stream>>>(F0, F0, idxk, w1, pre, 8192, 8192);
  hipMemsetAsync(gsum, 0, 256, stream);
  gn_reduce<<<dim3(8,8,2), 256, 0, stream>>>(pre, gsum, 4*8192*16);
  gn_act_max<32><<<(2*32*8192)/256, 256, 0, stream>>>(pre, gsum, g1, b1, F0a, 8192);

  // ---- FPS 8192 -> 2048
  fps_kernel<8,1024,2048><<<2, 1024, smem_f1, stream>>>(xyz, idx1);
  gather_kernel<<<(2*3*2048)/256, 256, 0, stream>>>(P1o, xyz, idx1, 3, 8192, 2048);
  gather_kernel<<<(2*32*2048)/256, 256, 0, stream>>>(F1sk, F0a, idx1, 32, 8192, 2048);

  // ---- stage 2
  knn_kernel<<<dim3(4096/256, 16), 256, 0, stream>>>(P1o, xyz, part_d, part_i, 2048, 8192, 512, 4096);
  knn_merge <<<4096/256, 256, 0, stream>>>(part_d, part_i, idxk, 256, 4096);
  edge_conv_pre<32,64><<<dim3(2048,2), 1024, smem_c2, stream>>>(F0a, F1sk, idxk, w2, pre, 2048, 8192);
  hipMemsetAsync(gsum, 0, 256, stream);
  gn_reduce<<<dim3(4,8,2), 256, 0, stream>>>(pre, gsum, 8*2048*16);
  gn_act_max<64><<<(2*64*2048)/256, 256, 0, stream>>>(pre, gsum, g2, b2, F1a, 2048);

  // ---- FPS 2048 -> 512
  fps_kernel<2,1024,512><<<2, 1024, smem_f2, stream>>>(P1o, idx2);
  gather_kernel<<<(2*3*512)/256, 256, 0, stream>>>(P2o, P1o, idx2, 3, 2048, 512);
  gather_kernel<<<(2*64*512)/256, 256, 0, stream>>>(F2sk, F1a, idx2, 64, 2048, 512);

  // ---- stage 3
  knn_kernel<<<dim3(1024/256, 8), 256, 0, stream>>>(P2o, P1o, part_d, part_i, 512, 2048, 256, 1024);
  knn_merge <<<1024/256, 256, 0, stream>>>(part_d, part_i, idxk, 128, 1024);
  edge_conv_pre<64,64><<<dim3(512,2), 1024, smem_c3, stream>>>(F1a, F2sk, idxk, w3, pre, 512, 2048);
  hipMemsetAsync(gsum, 0, 256, stream);
  gn_reduce<<<dim3(1,8,2), 256, 0, stream>>>(pre, gsum, 8*512*16);
  gn_act_max<64><<<(2*64*512)/256, 256, 0, stream>>>(pre, gsum, g3, b3, F2mid, 512);

  // ---- stage 4 (same knn idx)
  edge_conv_pre<64,128><<<dim3(512,2), 1024, smem_c4, stream>>>(F1a, F2mid, idxk, w4, pre, 512, 2048);
  hipMemsetAsync(gsum, 0, 256, stream);
  gn_reduce<<<dim3(2,8,2), 256, 0, stream>>>(pre, gsum, 16*512*16);
  gn_act_max<128><<<(2*128*512)/256, 256, 0, stream>>>(pre, gsum, g4, b4, F2a, 512);

  (void)in_sizes; (void)n_in; (void)out_size; (void)ws_size;
}

// Round 7
// 3702.122 us; speedup vs baseline: 1.2576x; 1.2410x over previous
//
#include <hip/hip_runtime.h>
#include <math.h>

typedef unsigned long long ull;

// ---------------------------------------------------------------------------
// stem: F0[b,o,n] = stem_w[o,:] . xyz[b,:,n] + stem_b[o]
// ---------------------------------------------------------------------------
__global__ __launch_bounds__(256) void stem_kernel(const float* __restrict__ xyz,
    const float* __restrict__ w, const float* __restrict__ bias,
    float* __restrict__ F0, int N){
  int id = blockIdx.x*256 + threadIdx.x;
  int n = id % N; int b = id / N;
  float x = xyz[((size_t)b*3+0)*N+n];
  float y = xyz[((size_t)b*3+1)*N+n];
  float z = xyz[((size_t)b*3+2)*N+n];
  #pragma unroll
  for (int o=0;o<8;o++){
    float v = fmaf(w[o*3+0],x, fmaf(w[o*3+1],y, fmaf(w[o*3+2],z, bias[o])));
    F0[((size_t)b*8+o)*N+n] = v;
  }
}

// ---------------------------------------------------------------------------
// KNN: per-thread top-16 over a candidate split; partials stored TRANSPOSED
// (row e = s*16+u, col qg) so both write and merge-read are coalesced.
// Distance mirrors reference: (qq + pp) - 2*dot, non-contracted IEEE ops.
// ---------------------------------------------------------------------------
__global__ __launch_bounds__(256) void knn_kernel(
    const float* __restrict__ Pq, const float* __restrict__ Pp,
    float* __restrict__ part_d, int* __restrict__ part_i,
    int Nq, int Np, int CAND, int total){
  __shared__ float4 tile[256];
  int qg = blockIdx.x*256 + threadIdx.x;
  int b  = qg / Nq, qn = qg % Nq;
  int s  = blockIdx.y;
  const float* Pqb = Pq + (size_t)b*3*Nq;
  const float* Ppb = Pp + (size_t)b*3*Np;
  float qx = Pqb[qn], qy = Pqb[Nq+qn], qz = Pqb[2*Nq+qn];
  float qq = __fadd_rn(__fadd_rn(__fmul_rn(qx,qx),__fmul_rn(qy,qy)),__fmul_rn(qz,qz));

  float dl[16]; int il[16];
  #pragma unroll
  for (int u=0;u<16;u++){ dl[u]=INFINITY; il[u]=-1; }
  float maxd = INFINITY; int maxslot = 0;

  int c0 = s*CAND;
  for (int tb=0; tb<CAND; tb+=256){
    int p = c0 + tb + threadIdx.x;
    float px = Ppb[p], py = Ppb[Np+p], pz = Ppb[2*Np+p];
    float pp = __fadd_rn(__fadd_rn(__fmul_rn(px,px),__fmul_rn(py,py)),__fmul_rn(pz,pz));
    __syncthreads();
    tile[threadIdx.x] = make_float4(px,py,pz,pp);
    __syncthreads();
    for (int j=0;j<256;j++){
      float4 c = tile[j];
      float dot = __fadd_rn(__fadd_rn(__fmul_rn(qx,c.x),__fmul_rn(qy,c.y)),__fmul_rn(qz,c.z));
      float dc  = __fsub_rn(__fadd_rn(qq,c.w), __fmul_rn(2.0f,dot));
      if (dc < maxd){
        int pidx = c0 + tb + j;
        #pragma unroll
        for (int u=0;u<16;u++){ bool sel=(maxslot==u); dl[u]=sel?dc:dl[u]; il[u]=sel?pidx:il[u]; }
        maxd = dl[0]; maxslot = 0;
        #pragma unroll
        for (int u=1;u<16;u++){ bool g=(dl[u]>maxd); maxd=g?dl[u]:maxd; maxslot=g?u:maxslot; }
      }
    }
  }
  #pragma unroll
  for (int u=0;u<16;u++){
    size_t row = (size_t)(s*16+u);
    part_d[row*total + qg] = dl[u];
    part_i[row*total + qg] = il[u];
  }
}

// merge transposed partials -> final 16 (lex (d, idx) smallest); coalesced reads
__global__ __launch_bounds__(256) void knn_merge(const float* __restrict__ part_d,
    const int* __restrict__ part_i, int* __restrict__ idxk, int rows, int total){
  int qg = blockIdx.x*256 + threadIdx.x;
  if (qg >= total) return;
  float dl[16]; int il[16];
  #pragma unroll
  for (int u=0;u<16;u++){ dl[u]=INFINITY; il[u]=0x7fffffff; }
  float maxd = INFINITY; int maxi = 0x7fffffff; int maxslot = 0;
  for (int e=0;e<rows;e++){
    float d = part_d[(size_t)e*total + qg];
    int  ii = part_i[(size_t)e*total + qg];
    bool better = (d < maxd) || (d == maxd && ii < maxi);
    if (better){
      #pragma unroll
      for (int u=0;u<16;u++){ bool sel=(maxslot==u); dl[u]=sel?d:dl[u]; il[u]=sel?ii:il[u]; }
      maxd = dl[0]; maxi = il[0]; maxslot = 0;
      #pragma unroll
      for (int u=1;u<16;u++){
        bool g = (dl[u]>maxd) || (dl[u]==maxd && il[u]>maxi);
        maxd=g?dl[u]:maxd; maxi=g?il[u]:maxi; maxslot=g?u:maxslot;
      }
    }
  }
  #pragma unroll
  for (int u=0;u<16;u++) idxk[(size_t)qg*16+u] = il[u];
}

// ---------------------------------------------------------------------------
// EdgeConv pre-activation
// ---------------------------------------------------------------------------
template<int CIN, int COUT>
__global__ __launch_bounds__(1024) void edge_conv_pre(
    const float* __restrict__ Fk, const float* __restrict__ Fi,
    const int* __restrict__ idx, const float* __restrict__ W,
    float* __restrict__ pre, int Nq, int Np){
  constexpr int C2  = 2*CIN;
  constexpr int PAD = C2 + 4;
  constexpr int TO  = (COUT <= 64) ? COUT : 64;
  constexpr int OP  = COUT / TO;
  extern __shared__ float sm[];
  float* Wl = sm;
  float* Pl = sm + COUT*PAD;
  int t = threadIdx.x;
  int n = blockIdx.x, b = blockIdx.y;
  for (int e=t; e<COUT*C2; e += blockDim.x){
    int o=e/C2, c=e%C2; Wl[o*PAD+c] = W[e];
  }
  const int* idxn = idx + ((size_t)b*Nq + n)*16;
  for (int e=t; e<16*C2; e += blockDim.x){
    int k = e/C2, c = e%C2;
    int cc = (c < CIN) ? c : (c-CIN);
    float fi = Fi[((size_t)b*CIN + cc)*Nq + n];
    float v;
    if (c < CIN){ int nb = idxn[k]; v = Fk[((size_t)b*CIN + c)*Np + nb] - fi; }
    else v = fi;
    Pl[k*PAD+c] = v;
  }
  __syncthreads();
  int k = t & 15, o0 = t >> 4;
  #pragma unroll
  for (int op=0; op<OP; op++){
    int o = o0 + op*TO;
    float acc = 0.f;
    #pragma unroll
    for (int c=0;c<C2;c+=4){
      float4 wv = *(const float4*)&Wl[o*PAD+c];
      float4 pv = *(const float4*)&Pl[k*PAD+c];
      acc = fmaf(wv.x,pv.x,acc); acc = fmaf(wv.y,pv.y,acc);
      acc = fmaf(wv.z,pv.z,acc); acc = fmaf(wv.w,pv.w,acc);
    }
    pre[(((size_t)b*COUT + o)*Nq + n)*16 + k] = acc;
  }
}

// GroupNorm stats
__global__ __launch_bounds__(256) void gn_reduce(const float* __restrict__ pre,
    double* __restrict__ gsum, int slabLen){
  int b = blockIdx.z, g = blockIdx.y;
  size_t base = ((size_t)(b*8+g))*slabLen;
  int chunkLen = slabLen / gridDim.x;
  const float* p = pre + base + (size_t)blockIdx.x*chunkLen;
  double s=0.0, sq=0.0;
  for (int i = threadIdx.x*4; i < chunkLen; i += 1024){
    float4 v = *(const float4*)(p+i);
    s += (double)v.x; sq = fma((double)v.x,(double)v.x,sq);
    s += (double)v.y; sq = fma((double)v.y,(double)v.y,sq);
    s += (double)v.z; sq = fma((double)v.z,(double)v.z,sq);
    s += (double)v.w; sq = fma((double)v.w,(double)v.w,sq);
  }
  #pragma unroll
  for (int off=32; off>=1; off>>=1){ s += __shfl_down(s, off); sq += __shfl_down(sq, off); }
  __shared__ double ls[4], lq[4];
  int wid = threadIdx.x>>6;
  if ((threadIdx.x&63)==0){ ls[wid]=s; lq[wid]=sq; }
  __syncthreads();
  if (threadIdx.x==0){
    double S=ls[0]+ls[1]+ls[2]+ls[3], Q=lq[0]+lq[1]+lq[2]+lq[3];
    atomicAdd(&gsum[(b*8+g)*2],   S);
    atomicAdd(&gsum[(b*8+g)*2+1], Q);
  }
}

// normalize + affine + relu + max over K
template<int COUT>
__global__ __launch_bounds__(256) void gn_act_max(const float* __restrict__ pre,
    const double* __restrict__ gsum, const float* __restrict__ gamma,
    const float* __restrict__ beta, float* __restrict__ outF, int Nq){
  int id = blockIdx.x*256 + threadIdx.x;
  int o = (id/Nq)%COUT; int b = id/(Nq*COUT);
  int g = o/(COUT/8);
  double s = gsum[(b*8+g)*2], sq = gsum[(b*8+g)*2+1];
  double cnt = (double)(COUT/8)*Nq*16.0;
  double mu  = s/cnt;
  double var = sq/cnt - mu*mu;
  float muf=(float)mu, rstd=(float)(1.0/sqrt(var+1e-5));
  float ga=gamma[o], be=beta[o];
  const float4* p = (const float4*)(pre + (size_t)id*16);
  float m = 0.f;
  #pragma unroll
  for (int q=0;q<4;q++){
    float4 v = p[q];
    m = fmaxf(m, fmaf((v.x-muf)*rstd, ga, be));
    m = fmaxf(m, fmaf((v.y-muf)*rstd, ga, be));
    m = fmaxf(m, fmaf((v.z-muf)*rstd, ga, be));
    m = fmaxf(m, fmaf((v.w-muf)*rstd, ga, be));
  }
  outF[id] = m;
}

// ---------------------------------------------------------------------------
// FPS v6: MINIMUM wave count. Evidence: r2 (512thr/PPT16)=910ns/iter,
// r5/r6 (1024thr/PPT8)=1183ns/iter — same update-issue floor (768 cyc),
// overhead scales with wave count (block reduce width, barrier skew, issue
// contention). So BLK=256 (1 wave/SIMD), PPT=32: block reduce = 4 keys,
// no issue contention. launch_bounds(BLK,1) = full VGPR budget for the
// 128-float register state (the old ",4" would cap at 128 and spill).
// Selection semantics identical to the validated round-2 path.
// ---------------------------------------------------------------------------
template<int CTRL>
__device__ __forceinline__ float dpp_maxf(float x){
  int y = __builtin_amdgcn_update_dpp(0, __float_as_int(x), CTRL, 0xf, 0xf, true);
  return fmaxf(x, __int_as_float(y));
}

template<int PPT, int BLK, int M>
__global__ __launch_bounds__(BLK, 1) void fps_kernel(const float* __restrict__ P,
    int* __restrict__ idx_out){
  constexpr int N  = PPT*BLK;
  constexpr int NW = BLK/64;
  extern __shared__ __align__(16) float sm[];
  float* lx = sm; float* ly = sm+N; float* lz = sm+2*N;
  ull* wk = (ull*)(sm + 3*N);               // 2*NW double-buffered keys
  int b = blockIdx.x, t = threadIdx.x;
  const float* Pb = P + (size_t)b*3*N;
  // coalesced global -> LDS
  for (int i=t; i<N; i+=BLK){ lx[i]=Pb[i]; ly[i]=Pb[N+i]; lz[i]=Pb[2*N+i]; }
  __syncthreads();
  // register-resident owned points (contiguous run of PPT)
  float px[PPT], py[PPT], pz[PPT], dist[PPT];
  #pragma unroll
  for (int j=0;j<PPT;j++){ int p=t*PPT+j; px[j]=lx[p]; py[j]=ly[p]; pz[j]=lz[p]; }
  // PIN: opaque touch — guarantees register residency of the coords.
  #pragma unroll
  for (int j=0;j<PPT;j++){
    asm volatile("" : "+v"(px[j]), "+v"(py[j]), "+v"(pz[j]));
  }
  float sx = lx[0], sy = ly[0], sz = lz[0];
  float bd = -1.f; int bj = 0;
  #pragma unroll
  for (int j=0;j<PPT;j++){
    float dx=__fsub_rn(px[j],sx), dy=__fsub_rn(py[j],sy), dz=__fsub_rn(pz[j],sz);
    float dd=__fadd_rn(__fadd_rn(__fmul_rn(dx,dx),__fmul_rn(dy,dy)),__fmul_rn(dz,dz));
    dist[j]=dd;
    bool c = dd > bd; bd = c?dd:bd; bj = c?j:bj;
  }
  int pbest = t*PPT + bj;
  if (t==0) idx_out[(size_t)b*M] = 0;
  int wid = t>>6, lane = t&63, par = 0;
  for (int i=1;i<M;i++){
    // wave max via DPP chain (full-wave max lands in lane 63)
    float r = bd;
    r = dpp_maxf<0x111>(r); r = dpp_maxf<0x112>(r);
    r = dpp_maxf<0x114>(r); r = dpp_maxf<0x118>(r);
    r = dpp_maxf<0x142>(r); r = dpp_maxf<0x143>(r);
    float wmax = __int_as_float(__builtin_amdgcn_readlane(__float_as_int(r), 63));
    ull msk = __ballot(bd == wmax);
    int srcl = __ffsll(msk) - 1;            // lowest lane == lowest owned index
    int wp = __builtin_amdgcn_readlane(pbest, srcl);
    if (lane==0)
      wk[par*NW + wid] = ((ull)__float_as_uint(wmax)<<32)
                       | (unsigned)(~(unsigned)wp);
    __syncthreads();
    ull best = wk[par*NW];
    #pragma unroll
    for (int w=1;w<NW;w++){ ull o = wk[par*NW+w]; best = (o>best)?o:best; }
    unsigned widx = ~(unsigned)best;
    if (t==0) idx_out[(size_t)b*M + i] = (int)widx;
    float nsx = lx[widx], nsy = ly[widx], nsz = lz[widx];
    par ^= 1;
    // register-only min-update + fused argmax scan
    float nbd = -1.f; int nbj = 0;
    #pragma unroll
    for (int j=0;j<PPT;j++){
      float dx=__fsub_rn(px[j],nsx), dy=__fsub_rn(py[j],nsy), dz=__fsub_rn(pz[j],nsz);
      float dd=__fadd_rn(__fadd_rn(__fmul_rn(dx,dx),__fmul_rn(dy,dy)),__fmul_rn(dz,dz));
      float nd = fminf(dist[j], dd);
      dist[j] = nd;
      bool c = nd > nbd; nbd = c?nd:nbd; nbj = c?j:nbj;
    }
    bd = nbd; pbest = t*PPT + nbj;
  }
}

// gather
__global__ __launch_bounds__(256) void gather_kernel(float* __restrict__ dst,
    const float* __restrict__ src, const int* __restrict__ idx,
    int C, int Nsrc, int M){
  int id = blockIdx.x*256 + threadIdx.x;
  int m = id % M; int c = (id/M)%C; int b = id/(M*C);
  dst[id] = src[((size_t)b*C + c)*Nsrc + idx[(size_t)b*M + m]];
}

// ---------------------------------------------------------------------------
extern "C" void kernel_launch(void* const* d_in, const int* in_sizes, int n_in,
                              void* d_out, int out_size, void* d_ws, size_t ws_size,
                              hipStream_t stream) {
  const float* xyz    = (const float*)d_in[0];
  const float* stem_w = (const float*)d_in[1];
  const float* stem_b = (const float*)d_in[2];
  const float* w1 = (const float*)d_in[3];
  const float* g1 = (const float*)d_in[4];
  const float* b1 = (const float*)d_in[5];
  const float* w2 = (const float*)d_in[6];
  const float* g2 = (const float*)d_in[7];
  const float* b2 = (const float*)d_in[8];
  const float* w3 = (const float*)d_in[9];
  const float* g3 = (const float*)d_in[10];
  const float* b3 = (const float*)d_in[11];
  const float* w4 = (const float*)d_in[12];
  const float* g4 = (const float*)d_in[13];
  const float* b4 = (const float*)d_in[14];

  float* out = (float*)d_out;
  float* P0o  = out + 0;
  float* F0a  = out + 49152;
  float* P1o  = out + 573440;
  float* F1a  = out + 585728;
  float* P2o  = out + 847872;
  float* F2a  = out + 850944;

  char* ws = (char*)d_ws;
  float* F0     = (float*)(ws + 0);
  float* pre    = (float*)(ws + 524288);
  float* part_d = (float*)(ws + 524288);
  int*   part_i = (int*)  (ws + 524288 + 16777216);
  int*   idxk   = (int*)  (ws + 34078720);
  double* gsum  = (double*)(ws + 35127296);
  int*   idx1   = (int*)  (ws + 35127552);
  int*   idx2   = (int*)  (ws + 35143936);
  float* F1sk   = (float*)(ws + 35148032);
  float* F2sk   = (float*)(ws + 35672320);
  float* F2mid  = (float*)(ws + 35934464);

  size_t smem_c1 = (size_t)(32*20  + 16*20 )*4;   // CIN=8  -> PAD=20
  size_t smem_c2 = (size_t)(64*68  + 16*68 )*4;   // CIN=32 -> PAD=68
  size_t smem_c3 = (size_t)(64*132 + 16*132)*4;   // CIN=64 -> PAD=132
  size_t smem_c4 = (size_t)(128*132+ 16*132)*4;   // CIN=64, COUT=128
  size_t smem_f1 = (size_t)3*8192*4 + 256;        // 96 KiB coords + keys
  size_t smem_f2 = (size_t)3*2048*4 + 256;

  hipMemcpyAsync(P0o, xyz, (size_t)49152*4, hipMemcpyDeviceToDevice, stream);
  stem_kernel<<<(2*8192)/256, 256, 0, stream>>>(xyz, stem_w, stem_b, F0, 8192);

  // ---- stage 1
  knn_kernel<<<dim3(16384/256, 16), 256, 0, stream>>>(xyz, xyz, part_d, part_i, 8192, 8192, 512, 16384);
  knn_merge <<<16384/256, 256, 0, stream>>>(part_d, part_i, idxk, 256, 16384);
  edge_conv_pre<8,32><<<dim3(8192,2), 512, smem_c1, stream>>>(F0, F0, idxk, w1, pre, 8192, 8192);
  hipMemsetAsync(gsum, 0, 256, stream);
  gn_reduce<<<dim3(8,8,2), 256, 0, stream>>>(pre, gsum, 4*8192*16);
  gn_act_max<32><<<(2*32*8192)/256, 256, 0, stream>>>(pre, gsum, g1, b1, F0a, 8192);

  // ---- FPS 8192 -> 2048
  fps_kernel<32,256,2048><<<2, 256, smem_f1, stream>>>(xyz, idx1);
  gather_kernel<<<(2*3*2048)/256, 256, 0, stream>>>(P1o, xyz, idx1, 3, 8192, 2048);
  gather_kernel<<<(2*32*2048)/256, 256, 0, stream>>>(F1sk, F0a, idx1, 32, 8192, 2048);

  // ---- stage 2
  knn_kernel<<<dim3(4096/256, 16), 256, 0, stream>>>(P1o, xyz, part_d, part_i, 2048, 8192, 512, 4096);
  knn_merge <<<4096/256, 256, 0, stream>>>(part_d, part_i, idxk, 256, 4096);
  edge_conv_pre<32,64><<<dim3(2048,2), 1024, smem_c2, stream>>>(F0a, F1sk, idxk, w2, pre, 2048, 8192);
  hipMemsetAsync(gsum, 0, 256, stream);
  gn_reduce<<<dim3(4,8,2), 256, 0, stream>>>(pre, gsum, 8*2048*16);
  gn_act_max<64><<<(2*64*2048)/256, 256, 0, stream>>>(pre, gsum, g2, b2, F1a, 2048);

  // ---- FPS 2048 -> 512
  fps_kernel<8,256,512><<<2, 256, smem_f2, stream>>>(P1o, idx2);
  gather_kernel<<<(2*3*512)/256, 256, 0, stream>>>(P2o, P1o, idx2, 3, 2048, 512);
  gather_kernel<<<(2*64*512)/256, 256, 0, stream>>>(F2sk, F1a, idx2, 64, 2048, 512);

  // ---- stage 3
  knn_kernel<<<dim3(1024/256, 8), 256, 0, stream>>>(P2o, P1o, part_d, part_i, 512, 2048, 256, 1024);
  knn_merge <<<1024/256, 256, 0, stream>>>(part_d, part_i, idxk, 128, 1024);
  edge_conv_pre<64,64><<<dim3(512,2), 1024, smem_c3, stream>>>(F1a, F2sk, idxk, w3, pre, 512, 2048);
  hipMemsetAsync(gsum, 0, 256, stream);
  gn_reduce<<<dim3(1,8,2), 256, 0, stream>>>(pre, gsum, 8*512*16);
  gn_act_max<64><<<(2*64*512)/256, 256, 0, stream>>>(pre, gsum, g3, b3, F2mid, 512);

  // ---- stage 4 (same knn idx)
  edge_conv_pre<64,128><<<dim3(512,2), 1024, smem_c4, stream>>>(F1a, F2mid, idxk, w4, pre, 512, 2048);
  hipMemsetAsync(gsum, 0, 256, stream);
  gn_reduce<<<dim3(2,8,2), 256, 0, stream>>>(pre, gsum, 16*512*16);
  gn_act_max<128><<<(2*128*512)/256, 256, 0, stream>>>(pre, gsum, g4, b4, F2a, 512);

  (void)in_sizes; (void)n_in; (void)out_size; (void)ws_size;
}

// Round 8
// 3484.352 us; speedup vs baseline: 1.3362x; 1.0625x over previous
//
#include <hip/hip_runtime.h>
#include <math.h>

typedef unsigned long long ull;

// ---------------------------------------------------------------------------
// stem + P0 passthrough: F0[b,o,n] = stem_w[o,:].xyz[b,:,n]+stem_b[o]; P0o=xyz
// ---------------------------------------------------------------------------
__global__ __launch_bounds__(256) void stem_fused(const float* __restrict__ xyz,
    const float* __restrict__ w, const float* __restrict__ bias,
    float* __restrict__ F0, float* __restrict__ P0o, int N){
  int id = blockIdx.x*256 + threadIdx.x;
  int n = id % N; int b = id / N;
  float x = xyz[((size_t)b*3+0)*N+n];
  float y = xyz[((size_t)b*3+1)*N+n];
  float z = xyz[((size_t)b*3+2)*N+n];
  P0o[((size_t)b*3+0)*N+n] = x;
  P0o[((size_t)b*3+1)*N+n] = y;
  P0o[((size_t)b*3+2)*N+n] = z;
  #pragma unroll
  for (int o=0;o<8;o++){
    float v = fmaf(w[o*3+0],x, fmaf(w[o*3+1],y, fmaf(w[o*3+2],z, bias[o])));
    F0[((size_t)b*8+o)*N+n] = v;
  }
}

// ---------------------------------------------------------------------------
// KNN fused (scan + merge in one kernel).
// 256 threads = 4 waves; wave w scans candidate split w for 64 queries
// (lane l = query blockIdx.x*64+l). Per-wave LDS tile staging (uniform
// barriers). Partials stored transposed in LDS (pd[u][s][q]: lane-consecutive
// q -> conflict-free). Final merge (threads 0..63) iterates s-outer/u-inner,
// lex (d, idx) smallest — semantics identical to the old knn_kernel+knn_merge.
// Distance mirrors reference: (qq+pp) - 2*dot, non-contracted IEEE ops.
// ---------------------------------------------------------------------------
__global__ __launch_bounds__(256) void knn_fused(
    const float* __restrict__ Pq, const float* __restrict__ Pp,
    int* __restrict__ idxk, int Nq, int Np){
  __shared__ float4 tile[4][256];
  __shared__ float  pd[16][4][64];
  __shared__ int    pi[16][4][64];
  int t = threadIdx.x, w = t>>6, l = t&63;
  int b = blockIdx.y;
  int qn = blockIdx.x*64 + l;
  const float* Pqb = Pq + (size_t)b*3*Nq;
  const float* Ppb = Pp + (size_t)b*3*Np;
  float qx = Pqb[qn], qy = Pqb[Nq+qn], qz = Pqb[2*Nq+qn];
  float qq = __fadd_rn(__fadd_rn(__fmul_rn(qx,qx),__fmul_rn(qy,qy)),__fmul_rn(qz,qz));

  float dl[16]; int il[16];
  #pragma unroll
  for (int u=0;u<16;u++){ dl[u]=INFINITY; il[u]=-1; }
  float maxd = INFINITY; int maxslot = 0;

  int CANDS = Np >> 2;                 // per-split candidates (multiple of 256)
  int c0 = w*CANDS;
  for (int tb=0; tb<CANDS; tb+=256){
    __syncthreads();
    #pragma unroll
    for (int k=0;k<4;k++){
      int p = c0 + tb + k*64 + l;
      float px = Ppb[p], py = Ppb[Np+p], pz = Ppb[2*Np+p];
      float pp = __fadd_rn(__fadd_rn(__fmul_rn(px,px),__fmul_rn(py,py)),__fmul_rn(pz,pz));
      tile[w][k*64+l] = make_float4(px,py,pz,pp);
    }
    __syncthreads();
    for (int j=0;j<256;j++){
      float4 c = tile[w][j];
      float dot = __fadd_rn(__fadd_rn(__fmul_rn(qx,c.x),__fmul_rn(qy,c.y)),__fmul_rn(qz,c.z));
      float dc  = __fsub_rn(__fadd_rn(qq,c.w), __fmul_rn(2.0f,dot));
      if (dc < maxd){
        int pidx = c0 + tb + j;
        #pragma unroll
        for (int u=0;u<16;u++){ bool sel=(maxslot==u); dl[u]=sel?dc:dl[u]; il[u]=sel?pidx:il[u]; }
        maxd = dl[0]; maxslot = 0;
        #pragma unroll
        for (int u=1;u<16;u++){ bool g=(dl[u]>maxd); maxd=g?dl[u]:maxd; maxslot=g?u:maxslot; }
      }
    }
  }
  #pragma unroll
  for (int u=0;u<16;u++){ pd[u][w][l]=dl[u]; pi[u][w][l]=il[u]; }
  __syncthreads();
  if (t < 64){
    int q = t;
    float mdl[16]; int mil[16];
    #pragma unroll
    for (int u=0;u<16;u++){ mdl[u]=INFINITY; mil[u]=0x7fffffff; }
    float mmaxd = INFINITY; int mmaxi = 0x7fffffff; int mslot = 0;
    for (int s=0;s<4;s++){
      #pragma unroll
      for (int u=0;u<16;u++){
        float d = pd[u][s][q]; int ii = pi[u][s][q];
        bool better = (d < mmaxd) || (d == mmaxd && ii < mmaxi);
        if (better){
          #pragma unroll
          for (int v=0;v<16;v++){ bool sel=(mslot==v); mdl[v]=sel?d:mdl[v]; mil[v]=sel?ii:mil[v]; }
          mmaxd = mdl[0]; mmaxi = mil[0]; mslot = 0;
          #pragma unroll
          for (int v=1;v<16;v++){
            bool g = (mdl[v]>mmaxd) || (mdl[v]==mmaxd && mil[v]>mmaxi);
            mmaxd=g?mdl[v]:mmaxd; mmaxi=g?mil[v]:mmaxi; mslot=g?v:mslot;
          }
        }
      }
    }
    #pragma unroll
    for (int u=0;u<16;u++)
      idxk[((size_t)b*Nq + blockIdx.x*64 + q)*16 + u] = mil[u];
  }
}

// ---------------------------------------------------------------------------
// EdgeConv pre-activation (unchanged from round 7 — proven)
// ---------------------------------------------------------------------------
template<int CIN, int COUT>
__global__ __launch_bounds__(1024) void edge_conv_pre(
    const float* __restrict__ Fk, const float* __restrict__ Fi,
    const int* __restrict__ idx, const float* __restrict__ W,
    float* __restrict__ pre, int Nq, int Np){
  constexpr int C2  = 2*CIN;
  constexpr int PAD = C2 + 4;
  constexpr int TO  = (COUT <= 64) ? COUT : 64;
  constexpr int OP  = COUT / TO;
  extern __shared__ float sm[];
  float* Wl = sm;
  float* Pl = sm + COUT*PAD;
  int t = threadIdx.x;
  int n = blockIdx.x, b = blockIdx.y;
  for (int e=t; e<COUT*C2; e += blockDim.x){
    int o=e/C2, c=e%C2; Wl[o*PAD+c] = W[e];
  }
  const int* idxn = idx + ((size_t)b*Nq + n)*16;
  for (int e=t; e<16*C2; e += blockDim.x){
    int k = e/C2, c = e%C2;
    int cc = (c < CIN) ? c : (c-CIN);
    float fi = Fi[((size_t)b*CIN + cc)*Nq + n];
    float v;
    if (c < CIN){ int nb = idxn[k]; v = Fk[((size_t)b*CIN + c)*Np + nb] - fi; }
    else v = fi;
    Pl[k*PAD+c] = v;
  }
  __syncthreads();
  int k = t & 15, o0 = t >> 4;
  #pragma unroll
  for (int op=0; op<OP; op++){
    int o = o0 + op*TO;
    float acc = 0.f;
    #pragma unroll
    for (int c=0;c<C2;c+=4){
      float4 wv = *(const float4*)&Wl[o*PAD+c];
      float4 pv = *(const float4*)&Pl[k*PAD+c];
      acc = fmaf(wv.x,pv.x,acc); acc = fmaf(wv.y,pv.y,acc);
      acc = fmaf(wv.z,pv.z,acc); acc = fmaf(wv.w,pv.w,acc);
    }
    pre[(((size_t)b*COUT + o)*Nq + n)*16 + k] = acc;
  }
}

// ---------------------------------------------------------------------------
// GroupNorm fused: one block per (group, batch). Phase 1: block-local double
// sum/sumsq over the contiguous slab (no atomics, no memset). Phase 2:
// normalize + affine + relu + max over K. Same arithmetic as before
// (double stats, float muf/rstd, fmaf((v-mu)*rstd, ga, be)).
// ---------------------------------------------------------------------------
template<int COUT>
__global__ __launch_bounds__(1024) void gn_fused(const float* __restrict__ pre,
    const float* __restrict__ gamma, const float* __restrict__ beta,
    float* __restrict__ outF, int Nq){
  constexpr int CPG = COUT/8;
  int g = blockIdx.x, b = blockIdx.y, t = threadIdx.x;
  size_t base = (((size_t)b*COUT + g*CPG)*(size_t)Nq)*16;
  const float* p = pre + base;
  int len = CPG*Nq*16;
  double s=0.0, sq=0.0;
  for (int i = t*4; i < len; i += 4096){
    float4 v = *(const float4*)(p+i);
    s += (double)v.x; sq = fma((double)v.x,(double)v.x,sq);
    s += (double)v.y; sq = fma((double)v.y,(double)v.y,sq);
    s += (double)v.z; sq = fma((double)v.z,(double)v.z,sq);
    s += (double)v.w; sq = fma((double)v.w,(double)v.w,sq);
  }
  #pragma unroll
  for (int off=32; off>=1; off>>=1){ s += __shfl_down(s, off); sq += __shfl_down(sq, off); }
  __shared__ double ls[16], lq[16];
  __shared__ float stats[2];
  int wid = t>>6;
  if ((t&63)==0){ ls[wid]=s; lq[wid]=sq; }
  __syncthreads();
  if (t==0){
    double S=0.0, Q=0.0;
    #pragma unroll
    for (int w=0;w<16;w++){ S+=ls[w]; Q+=lq[w]; }
    double cnt = (double)CPG*(double)Nq*16.0;
    double mu  = S/cnt;
    double var = Q/cnt - mu*mu;
    stats[0] = (float)mu;
    stats[1] = (float)(1.0/sqrt(var+1e-5));
  }
  __syncthreads();
  float muf = stats[0], rstd = stats[1];
  int outs = CPG*Nq;
  for (int e=t; e<outs; e+=1024){
    int ol = e/Nq, n = e - ol*Nq;
    int o = g*CPG + ol;
    float ga = gamma[o], be = beta[o];
    const float4* pp = (const float4*)(p + (size_t)e*16);
    float m = 0.f;
    #pragma unroll
    for (int q=0;q<4;q++){
      float4 v = pp[q];
      m = fmaxf(m, fmaf((v.x-muf)*rstd, ga, be));
      m = fmaxf(m, fmaf((v.y-muf)*rstd, ga, be));
      m = fmaxf(m, fmaf((v.z-muf)*rstd, ga, be));
      m = fmaxf(m, fmaf((v.w-muf)*rstd, ga, be));
    }
    outF[((size_t)b*COUT + o)*Nq + n] = m;
  }
}

// ---------------------------------------------------------------------------
// FPS (unchanged from round 7 — 256 threads, DPP reduce, register state)
// ---------------------------------------------------------------------------
template<int CTRL>
__device__ __forceinline__ float dpp_maxf(float x){
  int y = __builtin_amdgcn_update_dpp(0, __float_as_int(x), CTRL, 0xf, 0xf, true);
  return fmaxf(x, __int_as_float(y));
}

template<int PPT, int BLK, int M>
__global__ __launch_bounds__(BLK, 1) void fps_kernel(const float* __restrict__ P,
    int* __restrict__ idx_out){
  constexpr int N  = PPT*BLK;
  constexpr int NW = BLK/64;
  extern __shared__ __align__(16) float sm[];
  float* lx = sm; float* ly = sm+N; float* lz = sm+2*N;
  ull* wk = (ull*)(sm + 3*N);
  int b = blockIdx.x, t = threadIdx.x;
  const float* Pb = P + (size_t)b*3*N;
  for (int i=t; i<N; i+=BLK){ lx[i]=Pb[i]; ly[i]=Pb[N+i]; lz[i]=Pb[2*N+i]; }
  __syncthreads();
  float px[PPT], py[PPT], pz[PPT], dist[PPT];
  #pragma unroll
  for (int j=0;j<PPT;j++){ int p=t*PPT+j; px[j]=lx[p]; py[j]=ly[p]; pz[j]=lz[p]; }
  #pragma unroll
  for (int j=0;j<PPT;j++){
    asm volatile("" : "+v"(px[j]), "+v"(py[j]), "+v"(pz[j]));
  }
  float sx = lx[0], sy = ly[0], sz = lz[0];
  float bd = -1.f; int bj = 0;
  #pragma unroll
  for (int j=0;j<PPT;j++){
    float dx=__fsub_rn(px[j],sx), dy=__fsub_rn(py[j],sy), dz=__fsub_rn(pz[j],sz);
    float dd=__fadd_rn(__fadd_rn(__fmul_rn(dx,dx),__fmul_rn(dy,dy)),__fmul_rn(dz,dz));
    dist[j]=dd;
    bool c = dd > bd; bd = c?dd:bd; bj = c?j:bj;
  }
  int pbest = t*PPT + bj;
  if (t==0) idx_out[(size_t)b*M] = 0;
  int wid = t>>6, lane = t&63, par = 0;
  for (int i=1;i<M;i++){
    float r = bd;
    r = dpp_maxf<0x111>(r); r = dpp_maxf<0x112>(r);
    r = dpp_maxf<0x114>(r); r = dpp_maxf<0x118>(r);
    r = dpp_maxf<0x142>(r); r = dpp_maxf<0x143>(r);
    float wmax = __int_as_float(__builtin_amdgcn_readlane(__float_as_int(r), 63));
    ull msk = __ballot(bd == wmax);
    int srcl = __ffsll(msk) - 1;
    int wp = __builtin_amdgcn_readlane(pbest, srcl);
    if (lane==0)
      wk[par*NW + wid] = ((ull)__float_as_uint(wmax)<<32)
                       | (unsigned)(~(unsigned)wp);
    __syncthreads();
    ull best = wk[par*NW];
    #pragma unroll
    for (int w=1;w<NW;w++){ ull o = wk[par*NW+w]; best = (o>best)?o:best; }
    unsigned widx = ~(unsigned)best;
    if (t==0) idx_out[(size_t)b*M + i] = (int)widx;
    float nsx = lx[widx], nsy = ly[widx], nsz = lz[widx];
    par ^= 1;
    float nbd = -1.f; int nbj = 0;
    #pragma unroll
    for (int j=0;j<PPT;j++){
      float dx=__fsub_rn(px[j],nsx), dy=__fsub_rn(py[j],nsy), dz=__fsub_rn(pz[j],nsz);
      float dd=__fadd_rn(__fadd_rn(__fmul_rn(dx,dx),__fmul_rn(dy,dy)),__fmul_rn(dz,dz));
      float nd = fminf(dist[j], dd);
      dist[j] = nd;
      bool c = nd > nbd; nbd = c?nd:nbd; nbj = c?j:nbj;
    }
    bd = nbd; pbest = t*PPT + nbj;
  }
}

// ---------------------------------------------------------------------------
// fused gather: P (C=3) and F (C=CF) in one dispatch
// ---------------------------------------------------------------------------
__global__ __launch_bounds__(256) void gather_fused(float* __restrict__ Pdst,
    const float* __restrict__ Psrc, float* __restrict__ Fdst,
    const float* __restrict__ Fsrc, const int* __restrict__ idxv,
    int CF, int Nsrc, int M){
  int per = (3+CF)*M;
  int total = 2*per;
  for (int id = blockIdx.x*256 + threadIdx.x; id < total; id += gridDim.x*256){
    int b = id/per, r = id%per, c = r/M, m = r%M;
    int sn = idxv[(size_t)b*M + m];
    if (c < 3)
      Pdst[((size_t)b*3+c)*M+m] = Psrc[((size_t)b*3+c)*Nsrc+sn];
    else {
      int cf = c-3;
      Fdst[((size_t)b*CF+cf)*M+m] = Fsrc[((size_t)b*CF+cf)*Nsrc+sn];
    }
  }
}

// ---------------------------------------------------------------------------
extern "C" void kernel_launch(void* const* d_in, const int* in_sizes, int n_in,
                              void* d_out, int out_size, void* d_ws, size_t ws_size,
                              hipStream_t stream) {
  const float* xyz    = (const float*)d_in[0];
  const float* stem_w = (const float*)d_in[1];
  const float* stem_b = (const float*)d_in[2];
  const float* w1 = (const float*)d_in[3];
  const float* g1 = (const float*)d_in[4];
  const float* b1 = (const float*)d_in[5];
  const float* w2 = (const float*)d_in[6];
  const float* g2 = (const float*)d_in[7];
  const float* b2 = (const float*)d_in[8];
  const float* w3 = (const float*)d_in[9];
  const float* g3 = (const float*)d_in[10];
  const float* b3 = (const float*)d_in[11];
  const float* w4 = (const float*)d_in[12];
  const float* g4 = (const float*)d_in[13];
  const float* b4 = (const float*)d_in[14];

  float* out = (float*)d_out;
  float* P0o  = out + 0;
  float* F0a  = out + 49152;
  float* P1o  = out + 573440;
  float* F1a  = out + 585728;
  float* P2o  = out + 847872;
  float* F2a  = out + 850944;

  char* ws = (char*)d_ws;
  float* F0     = (float*)(ws + 0);          // 512 KB
  float* pre    = (float*)(ws + 524288);     // up to 33.5 MB
  int*   idxk   = (int*)  (ws + 34078720);   // 1 MB
  int*   idx1   = (int*)  (ws + 35127296);   // 16 KB
  int*   idx2   = (int*)  (ws + 35143680);   // 4 KB
  float* F1sk   = (float*)(ws + 35147776);   // 512 KB
  float* F2sk   = (float*)(ws + 35672064);   // 256 KB
  float* F2mid  = (float*)(ws + 35934208);   // 256 KB

  size_t smem_c1 = (size_t)(32*20  + 16*20 )*4;   // CIN=8  -> PAD=20
  size_t smem_c2 = (size_t)(64*68  + 16*68 )*4;   // CIN=32 -> PAD=68
  size_t smem_c3 = (size_t)(64*132 + 16*132)*4;   // CIN=64 -> PAD=132
  size_t smem_c4 = (size_t)(128*132+ 16*132)*4;   // CIN=64, COUT=128
  size_t smem_f1 = (size_t)3*8192*4 + 256;
  size_t smem_f2 = (size_t)3*2048*4 + 256;

  // ---- stage 1
  stem_fused<<<64, 256, 0, stream>>>(xyz, stem_w, stem_b, F0, P0o, 8192);
  knn_fused<<<dim3(128,2), 256, 0, stream>>>(xyz, xyz, idxk, 8192, 8192);
  edge_conv_pre<8,32><<<dim3(8192,2), 512, smem_c1, stream>>>(F0, F0, idxk, w1, pre, 8192, 8192);
  gn_fused<32><<<dim3(8,2), 1024, 0, stream>>>(pre, g1, b1, F0a, 8192);

  // ---- FPS 8192 -> 2048 + gathers
  fps_kernel<32,256,2048><<<2, 256, smem_f1, stream>>>(xyz, idx1);
  gather_fused<<<560, 256, 0, stream>>>(P1o, xyz, F1sk, F0a, idx1, 32, 8192, 2048);

  // ---- stage 2
  knn_fused<<<dim3(32,2), 256, 0, stream>>>(P1o, xyz, idxk, 2048, 8192);
  edge_conv_pre<32,64><<<dim3(2048,2), 1024, smem_c2, stream>>>(F0a, F1sk, idxk, w2, pre, 2048, 8192);
  gn_fused<64><<<dim3(8,2), 1024, 0, stream>>>(pre, g2, b2, F1a, 2048);

  // ---- FPS 2048 -> 512 + gathers
  fps_kernel<8,256,512><<<2, 256, smem_f2, stream>>>(P1o, idx2);
  gather_fused<<<268, 256, 0, stream>>>(P2o, P1o, F2sk, F1a, idx2, 64, 2048, 512);

  // ---- stage 3
  knn_fused<<<dim3(8,2), 256, 0, stream>>>(P2o, P1o, idxk, 512, 2048);
  edge_conv_pre<64,64><<<dim3(512,2), 1024, smem_c3, stream>>>(F1a, F2sk, idxk, w3, pre, 512, 2048);
  gn_fused<64><<<dim3(8,2), 1024, 0, stream>>>(pre, g3, b3, F2mid, 512);

  // ---- stage 4 (same knn idx)
  edge_conv_pre<64,128><<<dim3(512,2), 1024, smem_c4, stream>>>(F1a, F2mid, idxk, w4, pre, 512, 2048);
  gn_fused<128><<<dim3(8,2), 1024, 0, stream>>>(pre, g4, b4, F2a, 512);

  (void)in_sizes; (void)n_in; (void)out_size; (void)ws_size;
}